// Round 1
// baseline (7063.789 us; speedup 1.0000x reference)
//
#include <hip/hip_runtime.h>

#define D 300

namespace {

constexpr int kN   = 20000;   // atom nodes
constexpr int kNLG = 40000;   // line-graph nodes
constexpr int kE   = 80000;   // directed edges (main graph, layer 0)
constexpr int kELG = 200000;  // line-graph edges
constexpr int kL   = 5;

// ---------------- elementwise / gather kernels ----------------

__global__ void k_embed_pair(const int* __restrict__ idx, const float* __restrict__ t1,
                             const float* __restrict__ t2, float* __restrict__ out, int n) {
  int g = blockIdx.x * blockDim.x + threadIdx.x;
  if (g >= n * D) return;
  int i = g / D, d = g - i * D;
  out[g] = t1[idx[2 * i] * D + d] + t2[idx[2 * i + 1] * D + d];
}

// aggr[i] = prev[i] + (emb1[sl_idx] + emb2[0])   -- self-loop folded into init
__global__ void k_init_aggr(const float* __restrict__ prev, const float* __restrict__ emb1,
                            const float* __restrict__ emb2, int sl_idx,
                            float* __restrict__ aggr, int n) {
  int g = blockIdx.x * blockDim.x + threadIdx.x;
  if (g >= n * D) return;
  int d = g % D;
  aggr[g] = prev[g] + emb1[sl_idx * D + d] + emb2[d];
}

// layer 0 main graph: ea from embedding tables, edges = edge_index
__global__ void k_scatter_main0(const float* __restrict__ h, const int* __restrict__ ei,
                                const int* __restrict__ eattr, const float* __restrict__ emb1,
                                const float* __restrict__ emb2, float* __restrict__ aggr) {
  int g = blockIdx.x * blockDim.x + threadIdx.x;
  if (g >= kE * D) return;
  int k = g / D, d = g - k * D;
  int s = ei[k], t = ei[kE + k];
  float ea = emb1[eattr[2 * k] * D + d] + emb2[eattr[2 * k + 1] * D + d];
  atomicAdd(&aggr[t * D + d], h[s * D + d] + ea);
}

// layer >0 main graph: edges are lg map in both directions, ea = e_prev[j] for both
__global__ void k_scatter_mainL(const float* __restrict__ h, const float* __restrict__ e,
                                const int* __restrict__ map, float* __restrict__ aggr) {
  int g = blockIdx.x * blockDim.x + threadIdx.x;
  if (g >= kNLG * D) return;
  int j = g / D, d = g - j * D;
  int a = map[j], b = map[kNLG + j];
  float ev = e[g];
  atomicAdd(&aggr[b * D + d], h[a * D + d] + ev);
  atomicAdd(&aggr[a * D + d], h[b * D + d] + ev);
}

// layer 0 line graph: ea from tables indexed by x[map2[k]]
__global__ void k_scatter_lg0(const float* __restrict__ e, const int* __restrict__ lg_ei,
                              const int* __restrict__ map2, const int* __restrict__ x,
                              const float* __restrict__ emb1, const float* __restrict__ emb2,
                              float* __restrict__ aggr) {
  int g = blockIdx.x * blockDim.x + threadIdx.x;
  if (g >= kELG * D) return;
  int k = g / D, d = g - k * D;
  int s = lg_ei[k], t = lg_ei[kELG + k];
  int a = map2[k];
  float ea = emb1[x[2 * a] * D + d] + emb2[x[2 * a + 1] * D + d];
  atomicAdd(&aggr[t * D + d], e[s * D + d] + ea);
}

// layer >0 line graph: ea = h_prev[map2[k]]
__global__ void k_scatter_lgL(const float* __restrict__ e, const float* __restrict__ hprev,
                              const int* __restrict__ lg_ei, const int* __restrict__ map2,
                              float* __restrict__ aggr) {
  int g = blockIdx.x * blockDim.x + threadIdx.x;
  if (g >= kELG * D) return;
  int k = g / D, d = g - k * D;
  int s = lg_ei[k], t = lg_ei[kELG + k];
  float ea = hprev[map2[k] * D + d];
  atomicAdd(&aggr[t * D + d], e[s * D + d] + ea);
}

// ---------------- GEMM: C[M,N] = act(A[M,K] @ W[K,N] + bias) ----------------

#define BM 64
#define BN 64
#define BK 16
#define TM 4
#define TN 4

__global__ __launch_bounds__(256) void k_gemm(const float* __restrict__ A,
                                              const float* __restrict__ W,
                                              const float* __restrict__ bias,
                                              float* __restrict__ C,
                                              int M, int K, int N, int relu) {
  __shared__ float As[BK][BM + 4];
  __shared__ float Bs[BK][BN + 4];
  int block_row = blockIdx.y * BM;
  int block_col = blockIdx.x * BN;
  int tid = threadIdx.x;
  int tr = tid / 16, tc = tid % 16;
  float acc[TM][TN] = {};
  for (int k0 = 0; k0 < K; k0 += BK) {
    for (int i = tid; i < BM * BK; i += 256) {
      int r = i / BK, c = i - (i / BK) * BK;
      int gr = block_row + r, gc = k0 + c;
      As[c][r] = (gr < M && gc < K) ? A[gr * K + gc] : 0.f;
    }
    for (int i = tid; i < BK * BN; i += 256) {
      int r = i / BN, c = i - (i / BN) * BN;
      int gr = k0 + r, gc = block_col + c;
      Bs[r][c] = (gr < K && gc < N) ? W[gr * N + gc] : 0.f;
    }
    __syncthreads();
#pragma unroll
    for (int kk = 0; kk < BK; ++kk) {
      float a[TM], b[TN];
#pragma unroll
      for (int m = 0; m < TM; ++m) a[m] = As[kk][tr * TM + m];
#pragma unroll
      for (int n = 0; n < TN; ++n) b[n] = Bs[kk][tc * TN + n];
#pragma unroll
      for (int m = 0; m < TM; ++m)
#pragma unroll
        for (int n = 0; n < TN; ++n) acc[m][n] += a[m] * b[n];
    }
    __syncthreads();
  }
#pragma unroll
  for (int m = 0; m < TM; ++m) {
    int gr = block_row + tr * TM + m;
    if (gr >= M) continue;
#pragma unroll
    for (int n = 0; n < TN; ++n) {
      int gc = block_col + tc * TN + n;
      if (gc >= N) continue;
      float v = acc[m][n] + bias[gc];
      if (relu) v = fmaxf(v, 0.f);
      C[gr * N + gc] = v;
    }
  }
}

// ---------------- batchnorm ----------------

__global__ void k_zero(float* __restrict__ p, int n) {
  int g = blockIdx.x * blockDim.x + threadIdx.x;
  if (g < n) p[g] = 0.f;
}

__global__ void k_bn_stats(const float* __restrict__ X, int n,
                           float* __restrict__ sums, float* __restrict__ sumsq) {
  int tid = threadIdx.x;           // 256 threads; thread owns cols tid and tid+256
  int c0 = tid;
  int c1 = tid + 256;
  float s0 = 0.f, q0 = 0.f, s1 = 0.f, q1 = 0.f;
  int rpb = (n + gridDim.x - 1) / gridDim.x;
  int r0 = blockIdx.x * rpb;
  int r1 = min(n, r0 + rpb);
  for (int r = r0; r < r1; ++r) {
    float v0 = X[r * D + c0];
    s0 += v0; q0 += v0 * v0;
    if (c1 < D) {
      float v1 = X[r * D + c1];
      s1 += v1; q1 += v1 * v1;
    }
  }
  atomicAdd(&sums[c0], s0);
  atomicAdd(&sumsq[c0], q0);
  if (c1 < D) {
    atomicAdd(&sums[c1], s1);
    atomicAdd(&sumsq[c1], q1);
  }
}

__global__ void k_bn_apply(float* __restrict__ X, int n, const float* __restrict__ sums,
                           const float* __restrict__ sumsq, const float* __restrict__ gamma,
                           const float* __restrict__ beta, int relu) {
  int g = blockIdx.x * blockDim.x + threadIdx.x;
  if (g >= n * D) return;
  int c = g % D;
  float inv_n = 1.f / (float)n;
  float mu = sums[c] * inv_n;
  float var = sumsq[c] * inv_n - mu * mu;
  float rs = rsqrtf(var + 1e-5f);
  float v = (X[g] - mu) * rs * gamma[c] + beta[c];
  if (relu) v = fmaxf(v, 0.f);
  X[g] = v;
}

inline void launch_gemm(const float* A, const float* W, const float* bias, float* C,
                        int M, int K, int N, int relu, hipStream_t s) {
  dim3 grid((N + BN - 1) / BN, (M + BM - 1) / BM);
  k_gemm<<<grid, 256, 0, s>>>(A, W, bias, C, M, K, N, relu);
}

}  // namespace

extern "C" void kernel_launch(void* const* d_in, const int* in_sizes, int n_in,
                              void* d_out_v, int out_size, void* d_ws, size_t ws_size,
                              hipStream_t stream) {
  const int*   x            = (const int*)d_in[0];
  const int*   edge_index   = (const int*)d_in[1];
  const int*   edge_attr    = (const int*)d_in[2];
  const int*   lg_x         = (const int*)d_in[3];
  const int*   lg_edge_index= (const int*)d_in[4];
  const int*   lg_map       = (const int*)d_in[5];   // [2, N_LG]
  const int*   lg_map2      = (const int*)d_in[6];   // [E_LG]
  const float* node_emb1    = (const float*)d_in[7];
  const float* node_emb2    = (const float*)d_in[8];
  const float* gnn_e_emb1   = (const float*)d_in[9];
  const float* gnn_e_emb2   = (const float*)d_in[10];
  const float* g_emb1       = (const float*)d_in[11];  // [L,6,D]
  const float* g_emb2       = (const float*)d_in[12];  // [L,3,D]
  const float* g_w1         = (const float*)d_in[13];  // [L,D,2D]
  const float* g_b1         = (const float*)d_in[14];  // [L,2D]
  const float* g_w2         = (const float*)d_in[15];  // [L,2D,D]
  const float* g_b2         = (const float*)d_in[16];  // [L,D]
  const float* g_gamma      = (const float*)d_in[17];
  const float* g_beta       = (const float*)d_in[18];
  const float* lg_emb1      = (const float*)d_in[19];  // [L,120,D]
  const float* lg_emb2      = (const float*)d_in[20];  // [L,3,D]
  const float* lg_w1        = (const float*)d_in[21];
  const float* lg_b1        = (const float*)d_in[22];
  const float* lg_w2        = (const float*)d_in[23];
  const float* lg_b2        = (const float*)d_in[24];
  const float* lg_gamma     = (const float*)d_in[25];
  const float* lg_beta      = (const float*)d_in[26];

  float* out = (float*)d_out_v;
  char*  ws  = (char*)d_ws;
  float* aggr   = (float*)ws;                         // up to 40000*300 f32 = 48 MB
  float* hidden = (float*)(ws + 48000000);            // up to 40000*600 f32 = 96 MB
  float* stats  = (float*)(ws + 144000000);           // 600 f32 (sums | sumsq)

  // output layout: [6, 60000, 300]; h_list[l] rows 0..N, e_list[l] rows N..N+N_LG
  auto hptr = [&](int l) { return out + (size_t)l * 60000 * D; };
  auto eptr = [&](int l) { return out + ((size_t)l * 60000 + kN) * D; };

  dim3 b(256);

  // initial embeddings -> h_list[0], e_list[0]
  k_embed_pair<<<(kN * D + 255) / 256, b, 0, stream>>>(x, node_emb1, node_emb2, hptr(0), kN);
  k_embed_pair<<<(kNLG * D + 255) / 256, b, 0, stream>>>(lg_x, gnn_e_emb1, gnn_e_emb2, eptr(0), kNLG);

  for (int l = 0; l < kL; ++l) {
    const float* ge1 = g_emb1 + (size_t)l * 6 * D;
    const float* ge2 = g_emb2 + (size_t)l * 3 * D;
    const float* le1 = lg_emb1 + (size_t)l * 120 * D;
    const float* le2 = lg_emb2 + (size_t)l * 3 * D;
    float* hprev = hptr(l);
    float* eprev = eptr(l);
    float* hcur  = hptr(l + 1);
    float* ecur  = eptr(l + 1);
    int relu_tail = (l < kL - 1) ? 1 : 0;

    // -------- main-graph GINConv --------
    k_init_aggr<<<(kN * D + 255) / 256, b, 0, stream>>>(hprev, ge1, ge2, 4, aggr, kN);
    if (l == 0)
      k_scatter_main0<<<(kE * D + 255) / 256, b, 0, stream>>>(hprev, edge_index, edge_attr,
                                                              ge1, ge2, aggr);
    else
      k_scatter_mainL<<<(kNLG * D + 255) / 256, b, 0, stream>>>(hprev, eprev, lg_map, aggr);
    launch_gemm(aggr, g_w1 + (size_t)l * D * 2 * D, g_b1 + (size_t)l * 2 * D, hidden,
                kN, D, 2 * D, 1, stream);
    launch_gemm(hidden, g_w2 + (size_t)l * 2 * D * D, g_b2 + (size_t)l * D, hcur,
                kN, 2 * D, D, 0, stream);
    k_zero<<<3, b, 0, stream>>>(stats, 2 * D);
    k_bn_stats<<<256, b, 0, stream>>>(hcur, kN, stats, stats + D);
    k_bn_apply<<<(kN * D + 255) / 256, b, 0, stream>>>(hcur, kN, stats, stats + D,
                                                       g_gamma + (size_t)l * D,
                                                       g_beta + (size_t)l * D, relu_tail);

    // -------- line-graph GINConv --------
    k_init_aggr<<<(kNLG * D + 255) / 256, b, 0, stream>>>(eprev, le1, le2, 119, aggr, kNLG);
    if (l == 0)
      k_scatter_lg0<<<(kELG * D + 255) / 256, b, 0, stream>>>(eprev, lg_edge_index, lg_map2,
                                                              x, le1, le2, aggr);
    else
      k_scatter_lgL<<<(kELG * D + 255) / 256, b, 0, stream>>>(eprev, hprev, lg_edge_index,
                                                              lg_map2, aggr);
    launch_gemm(aggr, lg_w1 + (size_t)l * D * 2 * D, lg_b1 + (size_t)l * 2 * D, hidden,
                kNLG, D, 2 * D, 1, stream);
    launch_gemm(hidden, lg_w2 + (size_t)l * 2 * D * D, lg_b2 + (size_t)l * D, ecur,
                kNLG, 2 * D, D, 0, stream);
    k_zero<<<3, b, 0, stream>>>(stats, 2 * D);
    k_bn_stats<<<256, b, 0, stream>>>(ecur, kNLG, stats, stats + D);
    k_bn_apply<<<(kNLG * D + 255) / 256, b, 0, stream>>>(ecur, kNLG, stats, stats + D,
                                                         lg_gamma + (size_t)l * D,
                                                         lg_beta + (size_t)l * D, relu_tail);
  }
}

// Round 2
// 3815.400 us; speedup vs baseline: 1.8514x; 1.8514x over previous
//
#include <hip/hip_runtime.h>

#define D 300

namespace {

constexpr int kN   = 20000;
constexpr int kNLG = 40000;
constexpr int kE   = 80000;
constexpr int kELG = 200000;
constexpr int kL   = 5;

constexpr int K1P = 320;   // K=300 padded
constexpr int N1P = 640;   // N=600 padded
constexpr int K2P = 640;   // K=600 padded (hidden stride)
constexpr int N2P = 384;   // N=300 padded
constexpr int MPAD_MAX = 40064;

typedef __attribute__((ext_vector_type(8))) short short8;
typedef __attribute__((ext_vector_type(4))) float f32x4;

__device__ inline short f2bf(float f) {
  unsigned u = __float_as_uint(f);
  u += 0x7FFF + ((u >> 16) & 1);
  return (short)(u >> 16);
}

__device__ inline void gload_lds16(const void* g, void* l) {
  __builtin_amdgcn_global_load_lds(
      (const __attribute__((address_space(1))) void*)g,
      (__attribute__((address_space(3))) void*)l, 16, 0, 0);
}

// ---------------- elementwise / gather kernels ----------------

__global__ void k_embed_pair(const int* __restrict__ idx, const float* __restrict__ t1,
                             const float* __restrict__ t2, float* __restrict__ out, int n) {
  int g = blockIdx.x * blockDim.x + threadIdx.x;
  if (g >= n * D) return;
  int i = g / D, d = g - i * D;
  out[g] = t1[idx[2 * i] * D + d] + t2[idx[2 * i + 1] * D + d];
}

__global__ void k_init_aggr(const float* __restrict__ prev, const float* __restrict__ emb1,
                            const float* __restrict__ emb2, int sl_idx,
                            float* __restrict__ aggr, int n) {
  int g = blockIdx.x * blockDim.x + threadIdx.x;
  if (g >= n * D) return;
  int d = g % D;
  aggr[g] = prev[g] + emb1[sl_idx * D + d] + emb2[d];
}

__global__ void k_scatter_main0(const float* __restrict__ h, const int* __restrict__ ei,
                                const int* __restrict__ eattr, const float* __restrict__ emb1,
                                const float* __restrict__ emb2, float* __restrict__ aggr) {
  int g = blockIdx.x * blockDim.x + threadIdx.x;
  if (g >= kE * D) return;
  int k = g / D, d = g - k * D;
  int s = ei[k], t = ei[kE + k];
  float ea = emb1[eattr[2 * k] * D + d] + emb2[eattr[2 * k + 1] * D + d];
  atomicAdd(&aggr[t * D + d], h[s * D + d] + ea);
}

__global__ void k_scatter_mainL(const float* __restrict__ h, const float* __restrict__ e,
                                const int* __restrict__ map, float* __restrict__ aggr) {
  int g = blockIdx.x * blockDim.x + threadIdx.x;
  if (g >= kNLG * D) return;
  int j = g / D, d = g - j * D;
  int a = map[j], b = map[kNLG + j];
  float ev = e[g];
  atomicAdd(&aggr[b * D + d], h[a * D + d] + ev);
  atomicAdd(&aggr[a * D + d], h[b * D + d] + ev);
}

__global__ void k_scatter_lg0(const float* __restrict__ e, const int* __restrict__ lg_ei,
                              const int* __restrict__ map2, const int* __restrict__ x,
                              const float* __restrict__ emb1, const float* __restrict__ emb2,
                              float* __restrict__ aggr) {
  int g = blockIdx.x * blockDim.x + threadIdx.x;
  if (g >= kELG * D) return;
  int k = g / D, d = g - k * D;
  int s = lg_ei[k], t = lg_ei[kELG + k];
  int a = map2[k];
  float ea = emb1[x[2 * a] * D + d] + emb2[x[2 * a + 1] * D + d];
  atomicAdd(&aggr[t * D + d], e[s * D + d] + ea);
}

__global__ void k_scatter_lgL(const float* __restrict__ e, const float* __restrict__ hprev,
                              const int* __restrict__ lg_ei, const int* __restrict__ map2,
                              float* __restrict__ aggr) {
  int g = blockIdx.x * blockDim.x + threadIdx.x;
  if (g >= kELG * D) return;
  int k = g / D, d = g - k * D;
  int s = lg_ei[k], t = lg_ei[kELG + k];
  float ea = hprev[map2[k] * D + d];
  atomicAdd(&aggr[t * D + d], e[s * D + d] + ea);
}

// ---------------- conversions ----------------

// W fp32 [Lc][K][N] -> Wt bf16 [Lc][Npad][Kpad] transposed, zero-padded
__global__ void k_convert_wt(const float* __restrict__ W, short* __restrict__ Wt,
                             int Lc, int K, int Nn, int Kpad, int Npad) {
  int g = blockIdx.x * blockDim.x + threadIdx.x;
  int per = Npad * Kpad;
  if (g >= Lc * per) return;
  int l = g / per, rem = g - l * per;
  int n = rem / Kpad, k = rem - n * Kpad;
  float v = (n < Nn && k < K) ? W[(size_t)l * K * Nn + (size_t)k * Nn + n] : 0.f;
  Wt[g] = f2bf(v);
}

// aggr fp32 [M][300] -> bf16 [Mpad][320] zero-padded
__global__ void k_convert_a(const float* __restrict__ A, short* __restrict__ Ab,
                            int M, int Mpad) {
  int g = blockIdx.x * blockDim.x + threadIdx.x;
  if (g >= Mpad * K1P) return;
  int r = g / K1P, c = g - r * K1P;
  float v = (r < M && c < D) ? A[r * D + c] : 0.f;
  Ab[g] = f2bf(v);
}

// ---------------- MFMA GEMM ----------------
// C[M x Ncols] = act(A[Mpad x Kpad](bf16) @ Bt^T + bias)
// Bt is [Npad x Kpad] bf16 (pre-transposed weights). Tile 128x128xBK32.

template<bool RELU, bool OUT_BF16>
__global__ __launch_bounds__(256) void k_mfma_gemm(
    const short* __restrict__ A, const short* __restrict__ Bt,
    const float* __restrict__ bias, int biasN,
    void* __restrict__ Cv, int Crows, int Ccols, int Cstride, int Kpad) {
  __shared__ __align__(16) short ldsA[128 * 32];
  __shared__ __align__(16) short ldsB[128 * 32];
  const int tid = threadIdx.x;
  const int lane = tid & 63, w = tid >> 6;
  const int brow = blockIdx.y * 128;
  const int bcol = blockIdx.x * 128;
  const int wr = w >> 1, wc = w & 1;

  f32x4 acc[4][4] = {};

  const int sr = tid >> 2;            // staging row (0..63)
  const int sc = (tid & 3) * 8;       // staging col in shorts (16B chunks)
  char* la = (char*)ldsA + w * 1024;  // wave-uniform LDS dest (HW adds lane*16)
  char* lb = (char*)ldsB + w * 1024;

  for (int k0 = 0; k0 < Kpad; k0 += 32) {
    __syncthreads();
    const short* gA0 = A + (size_t)(brow + sr) * Kpad + (k0 + sc);
    const short* gB0 = Bt + (size_t)(bcol + sr) * Kpad + (k0 + sc);
    gload_lds16(gA0, la);
    gload_lds16(gA0 + (size_t)64 * Kpad, la + 4096);
    gload_lds16(gB0, lb);
    gload_lds16(gB0 + (size_t)64 * Kpad, lb + 4096);
    __syncthreads();

    const int kq = (lane >> 4) * 16;  // byte offset of this lane's 8 bf16 in the 32-K row
    short8 af[4], bf[4];
#pragma unroll
    for (int m = 0; m < 4; ++m) {
      int row = wr * 64 + m * 16 + (lane & 15);
      af[m] = *(const short8*)((const char*)ldsA + row * 64 + kq);
    }
#pragma unroll
    for (int n = 0; n < 4; ++n) {
      int col = wc * 64 + n * 16 + (lane & 15);
      bf[n] = *(const short8*)((const char*)ldsB + col * 64 + kq);
    }
#pragma unroll
    for (int m = 0; m < 4; ++m)
#pragma unroll
      for (int n = 0; n < 4; ++n)
        acc[m][n] = __builtin_amdgcn_mfma_f32_16x16x32_bf16(af[m], bf[n], acc[m][n], 0, 0, 0);
  }

  const int r0 = brow + wr * 64;
  const int c0 = bcol + wc * 64;
#pragma unroll
  for (int m = 0; m < 4; ++m) {
#pragma unroll
    for (int i = 0; i < 4; ++i) {
      int row = r0 + m * 16 + (lane >> 4) * 4 + i;
      if (row >= Crows) continue;
#pragma unroll
      for (int n = 0; n < 4; ++n) {
        int col = c0 + n * 16 + (lane & 15);
        if (col >= Ccols) continue;
        float b = (col < biasN) ? bias[col] : 0.f;
        float v = acc[m][n][i] + b;
        if (RELU) v = fmaxf(v, 0.f);
        if (OUT_BF16)
          ((short*)Cv)[(size_t)row * Cstride + col] = f2bf(v);
        else
          ((float*)Cv)[(size_t)row * Cstride + col] = v;
      }
    }
  }
}

// ---------------- batchnorm ----------------

__global__ void k_zero(float* __restrict__ p, int n) {
  int g = blockIdx.x * blockDim.x + threadIdx.x;
  if (g < n) p[g] = 0.f;
}

__global__ void k_bn_stats(const float* __restrict__ X, int n,
                           float* __restrict__ sums, float* __restrict__ sumsq) {
  int tid = threadIdx.x;
  int c0 = tid, c1 = tid + 256;
  float s0 = 0.f, q0 = 0.f, s1 = 0.f, q1 = 0.f;
  int rpb = (n + gridDim.x - 1) / gridDim.x;
  int r0 = blockIdx.x * rpb;
  int r1 = min(n, r0 + rpb);
  for (int r = r0; r < r1; ++r) {
    float v0 = X[r * D + c0];
    s0 += v0; q0 += v0 * v0;
    if (c1 < D) {
      float v1 = X[r * D + c1];
      s1 += v1; q1 += v1 * v1;
    }
  }
  atomicAdd(&sums[c0], s0);
  atomicAdd(&sumsq[c0], q0);
  if (c1 < D) {
    atomicAdd(&sums[c1], s1);
    atomicAdd(&sumsq[c1], q1);
  }
}

__global__ void k_bn_apply(float* __restrict__ X, int n, const float* __restrict__ sums,
                           const float* __restrict__ sumsq, const float* __restrict__ gamma,
                           const float* __restrict__ beta, int relu) {
  int g = blockIdx.x * blockDim.x + threadIdx.x;
  if (g >= n * D) return;
  int c = g % D;
  float inv_n = 1.f / (float)n;
  float mu = sums[c] * inv_n;
  float var = sumsq[c] * inv_n - mu * mu;
  float rs = rsqrtf(var + 1e-5f);
  float v = (X[g] - mu) * rs * gamma[c] + beta[c];
  if (relu) v = fmaxf(v, 0.f);
  X[g] = v;
}

}  // namespace

extern "C" void kernel_launch(void* const* d_in, const int* in_sizes, int n_in,
                              void* d_out_v, int out_size, void* d_ws, size_t ws_size,
                              hipStream_t stream) {
  const int*   x            = (const int*)d_in[0];
  const int*   edge_index   = (const int*)d_in[1];
  const int*   edge_attr    = (const int*)d_in[2];
  const int*   lg_x         = (const int*)d_in[3];
  const int*   lg_edge_index= (const int*)d_in[4];
  const int*   lg_map       = (const int*)d_in[5];
  const int*   lg_map2      = (const int*)d_in[6];
  const float* node_emb1    = (const float*)d_in[7];
  const float* node_emb2    = (const float*)d_in[8];
  const float* gnn_e_emb1   = (const float*)d_in[9];
  const float* gnn_e_emb2   = (const float*)d_in[10];
  const float* g_emb1       = (const float*)d_in[11];
  const float* g_emb2       = (const float*)d_in[12];
  const float* g_w1         = (const float*)d_in[13];
  const float* g_b1         = (const float*)d_in[14];
  const float* g_w2         = (const float*)d_in[15];
  const float* g_b2         = (const float*)d_in[16];
  const float* g_gamma      = (const float*)d_in[17];
  const float* g_beta       = (const float*)d_in[18];
  const float* lg_emb1      = (const float*)d_in[19];
  const float* lg_emb2      = (const float*)d_in[20];
  const float* lg_w1        = (const float*)d_in[21];
  const float* lg_b1        = (const float*)d_in[22];
  const float* lg_w2        = (const float*)d_in[23];
  const float* lg_b2        = (const float*)d_in[24];
  const float* lg_gamma     = (const float*)d_in[25];
  const float* lg_beta      = (const float*)d_in[26];

  float* out = (float*)d_out_v;
  char*  ws  = (char*)d_ws;

  // workspace layout (256B aligned)
  size_t off = 0;
  auto alloc = [&](size_t bytes) { void* p = ws + off; off = (off + bytes + 255) & ~(size_t)255; return p; };
  float* aggr    = (float*)alloc((size_t)MPAD_MAX * D * 4);        // 48.1 MB
  short* aggr_b  = (short*)alloc((size_t)MPAD_MAX * K1P * 2);      // 25.6 MB
  short* hidden  = (short*)alloc((size_t)MPAD_MAX * N1P * 2);      // 51.3 MB
  short* g_w1t   = (short*)alloc((size_t)kL * N1P * K1P * 2);      // 2.0 MB
  short* g_w2t   = (short*)alloc((size_t)kL * N2P * K2P * 2);      // 2.5 MB
  short* lg_w1t  = (short*)alloc((size_t)kL * N1P * K1P * 2);
  short* lg_w2t  = (short*)alloc((size_t)kL * N2P * K2P * 2);
  float* stats   = (float*)alloc(600 * 4);

  auto hptr = [&](int l) { return out + (size_t)l * 60000 * D; };
  auto eptr = [&](int l) { return out + ((size_t)l * 60000 + kN) * D; };

  dim3 b(256);

  // weight transpose-conversions (all layers, 4 launches)
  {
    int tot1 = kL * N1P * K1P, tot2 = kL * N2P * K2P;
    k_convert_wt<<<(tot1 + 255) / 256, b, 0, stream>>>(g_w1, g_w1t, kL, D, 2 * D, K1P, N1P);
    k_convert_wt<<<(tot2 + 255) / 256, b, 0, stream>>>(g_w2, g_w2t, kL, 2 * D, D, K2P, N2P);
    k_convert_wt<<<(tot1 + 255) / 256, b, 0, stream>>>(lg_w1, lg_w1t, kL, D, 2 * D, K1P, N1P);
    k_convert_wt<<<(tot2 + 255) / 256, b, 0, stream>>>(lg_w2, lg_w2t, kL, 2 * D, D, K2P, N2P);
  }

  k_embed_pair<<<(kN * D + 255) / 256, b, 0, stream>>>(x, node_emb1, node_emb2, hptr(0), kN);
  k_embed_pair<<<(kNLG * D + 255) / 256, b, 0, stream>>>(lg_x, gnn_e_emb1, gnn_e_emb2, eptr(0), kNLG);

  for (int l = 0; l < kL; ++l) {
    const float* ge1 = g_emb1 + (size_t)l * 6 * D;
    const float* ge2 = g_emb2 + (size_t)l * 3 * D;
    const float* le1 = lg_emb1 + (size_t)l * 120 * D;
    const float* le2 = lg_emb2 + (size_t)l * 3 * D;
    float* hprev = hptr(l);
    float* eprev = eptr(l);
    float* hcur  = hptr(l + 1);
    float* ecur  = eptr(l + 1);
    int relu_tail = (l < kL - 1) ? 1 : 0;

    // -------- main-graph GINConv (M = 20000) --------
    {
      const int M = kN, Mpad = 20096, mt = Mpad / 128;
      k_init_aggr<<<(M * D + 255) / 256, b, 0, stream>>>(hprev, ge1, ge2, 4, aggr, M);
      if (l == 0)
        k_scatter_main0<<<(kE * D + 255) / 256, b, 0, stream>>>(hprev, edge_index, edge_attr,
                                                                ge1, ge2, aggr);
      else
        k_scatter_mainL<<<(kNLG * D + 255) / 256, b, 0, stream>>>(hprev, eprev, lg_map, aggr);
      k_convert_a<<<(Mpad * K1P + 255) / 256, b, 0, stream>>>(aggr, aggr_b, M, Mpad);
      k_mfma_gemm<true, true><<<dim3(N1P / 128, mt), b, 0, stream>>>(
          aggr_b, g_w1t + (size_t)l * N1P * K1P, g_b1 + (size_t)l * 2 * D, 2 * D,
          hidden, Mpad, N1P, N1P, K1P);
      k_mfma_gemm<false, false><<<dim3(N2P / 128, mt), b, 0, stream>>>(
          hidden, g_w2t + (size_t)l * N2P * K2P, g_b2 + (size_t)l * D, D,
          hcur, M, D, D, K2P);
      k_zero<<<3, b, 0, stream>>>(stats, 2 * D);
      k_bn_stats<<<256, b, 0, stream>>>(hcur, M, stats, stats + D);
      k_bn_apply<<<(M * D + 255) / 256, b, 0, stream>>>(hcur, M, stats, stats + D,
                                                        g_gamma + (size_t)l * D,
                                                        g_beta + (size_t)l * D, relu_tail);
    }

    // -------- line-graph GINConv (M = 40000) --------
    {
      const int M = kNLG, Mpad = 40064, mt = Mpad / 128;
      k_init_aggr<<<(M * D + 255) / 256, b, 0, stream>>>(eprev, le1, le2, 119, aggr, M);
      if (l == 0)
        k_scatter_lg0<<<(kELG * D + 255) / 256, b, 0, stream>>>(eprev, lg_edge_index, lg_map2,
                                                                x, le1, le2, aggr);
      else
        k_scatter_lgL<<<(kELG * D + 255) / 256, b, 0, stream>>>(eprev, hprev, lg_edge_index,
                                                                lg_map2, aggr);
      k_convert_a<<<(Mpad * K1P + 255) / 256, b, 0, stream>>>(aggr, aggr_b, M, Mpad);
      k_mfma_gemm<true, true><<<dim3(N1P / 128, mt), b, 0, stream>>>(
          aggr_b, lg_w1t + (size_t)l * N1P * K1P, lg_b1 + (size_t)l * 2 * D, 2 * D,
          hidden, Mpad, N1P, N1P, K1P);
      k_mfma_gemm<false, false><<<dim3(N2P / 128, mt), b, 0, stream>>>(
          hidden, lg_w2t + (size_t)l * N2P * K2P, lg_b2 + (size_t)l * D, D,
          ecur, M, D, D, K2P);
      k_zero<<<3, b, 0, stream>>>(stats, 2 * D);
      k_bn_stats<<<256, b, 0, stream>>>(ecur, M, stats, stats + D);
      k_bn_apply<<<(M * D + 255) / 256, b, 0, stream>>>(ecur, M, stats, stats + D,
                                                        lg_gamma + (size_t)l * D,
                                                        lg_beta + (size_t)l * D, relu_tail);
    }
  }
}

// Round 4
// 2612.208 us; speedup vs baseline: 2.7041x; 1.4606x over previous
//
#include <hip/hip_runtime.h>

#define D 300

namespace {

constexpr int kN   = 20000;
constexpr int kNLG = 40000;
constexpr int kE   = 80000;
constexpr int kELG = 200000;
constexpr int kL   = 5;

constexpr int K1P = 320;   // K=300 padded
constexpr int N1P = 640;   // N=600 padded
constexpr int K2P = 640;   // K=600 padded (hidden stride)
constexpr int N2P = 384;   // N=300 padded
constexpr int MP_N   = 20096;  // 20000 padded to 128
constexpr int MP_NLG = 40064;  // 40000 padded to 128

typedef __attribute__((ext_vector_type(8))) _Float16 half8;
typedef __attribute__((ext_vector_type(4))) float f32x4;

__device__ inline short f2h(float f) {
  _Float16 h = (_Float16)f;  // v_cvt_f16_f32, RTN
  return *(short*)&h;
}

__device__ inline void gload_lds16(const void* g, void* l) {
  __builtin_amdgcn_global_load_lds(
      (const __attribute__((address_space(1))) void*)g,
      (__attribute__((address_space(3))) void*)l, 16, 0, 0);
}

// ---------------- CSR build ----------------

__global__ void k_zero_int(int* __restrict__ p, int n) {
  int g = blockIdx.x * blockDim.x + threadIdx.x;
  if (g < n) p[g] = 0;
}

__global__ void k_zero_short(short* __restrict__ p, int n) {
  int g = blockIdx.x * blockDim.x + threadIdx.x;
  if (g < n) p[g] = 0;
}

__global__ void k_hist(const int* __restrict__ dst, int n, int* __restrict__ deg) {
  int g = blockIdx.x * blockDim.x + threadIdx.x;
  if (g < n) atomicAdd(&deg[dst[g]], 1);
}

// single-block exclusive scan: deg (in cursor) -> offs[0..n], cursor rewritten to base
__global__ __launch_bounds__(256) void k_scan(int* __restrict__ cursor,
                                              int* __restrict__ offs, int n) {
  __shared__ int part[256];
  int tid = threadIdx.x;
  int chunk = (n + 255) / 256;
  int s0 = tid * chunk;
  int s1 = min(n, s0 + chunk);
  int sum = 0;
  for (int i = s0; i < s1; ++i) sum += cursor[i];
  part[tid] = sum;
  __syncthreads();
  for (int off = 1; off < 256; off <<= 1) {
    int v = (tid >= off) ? part[tid - off] : 0;
    __syncthreads();
    part[tid] += v;
    __syncthreads();
  }
  int run = (tid == 0) ? 0 : part[tid - 1];
  for (int i = s0; i < s1; ++i) {
    int dv = cursor[i];
    offs[i] = run;
    cursor[i] = run;
    run += dv;
  }
  if (tid == 255) offs[n] = run;
}

__global__ void k_fill(const int* __restrict__ dst, int n, int idbase,
                       int* __restrict__ cursor, int* __restrict__ perm) {
  int g = blockIdx.x * blockDim.x + threadIdx.x;
  if (g < n) {
    int pos = atomicAdd(&cursor[dst[g]], 1);
    perm[pos] = idbase + g;
  }
}

// ---------------- fused gather kernels (CSR) ----------------
// one 64-lane wave per destination node; acc in 5 regs; writes fp16 padded row

#define GATHER_HEAD(NNODES)                                   \
  int node = blockIdx.x * 4 + (threadIdx.x >> 6);             \
  int lane = threadIdx.x & 63;                                \
  if (node >= (NNODES)) return;                               \
  float acc[5];

#define GATHER_TAIL(OUT)                                      \
  _Pragma("unroll")                                           \
  for (int q = 0; q < 5; ++q) {                               \
    int d = lane + q * 64;                                    \
    (OUT)[(size_t)node * K1P + d] = (d < D) ? f2h(acc[q]) : (short)0; \
  }

// main graph, layer 0: edges = edge_index, ea from tables
__global__ void k_gather_m0(const float* __restrict__ hprev, const int* __restrict__ src,
                            const int* __restrict__ eattr, const float* __restrict__ emb1,
                            const float* __restrict__ emb2, const int* __restrict__ offs,
                            const int* __restrict__ perm, short* __restrict__ out) {
  GATHER_HEAD(kN)
#pragma unroll
  for (int q = 0; q < 5; ++q) {
    int d = lane + q * 64;
    acc[q] = (d < D) ? hprev[(size_t)node * D + d] + emb1[4 * D + d] + emb2[d] : 0.f;
  }
  int p1 = offs[node + 1];
  for (int p = offs[node]; p < p1; ++p) {
    int k = perm[p];
    const float* hs = hprev + (size_t)src[k] * D;
    const float* e1 = emb1 + (size_t)eattr[2 * k] * D;
    const float* e2 = emb2 + (size_t)eattr[2 * k + 1] * D;
#pragma unroll
    for (int q = 0; q < 5; ++q) {
      int d = lane + q * 64;
      if (d < D) acc[q] += hs[d] + e1[d] + e2[d];
    }
  }
  GATHER_TAIL(out)
}

// main graph, layers >0: src(id)=lg_map[id], attr row = id mod 40000 of eprev
__global__ void k_gather_mL(const float* __restrict__ hprev, const float* __restrict__ eprev,
                            const int* __restrict__ lg_map, const float* __restrict__ emb1,
                            const float* __restrict__ emb2, const int* __restrict__ offs,
                            const int* __restrict__ perm, short* __restrict__ out) {
  GATHER_HEAD(kN)
#pragma unroll
  for (int q = 0; q < 5; ++q) {
    int d = lane + q * 64;
    acc[q] = (d < D) ? hprev[(size_t)node * D + d] + emb1[4 * D + d] + emb2[d] : 0.f;
  }
  int p1 = offs[node + 1];
  for (int p = offs[node]; p < p1; ++p) {
    int id = perm[p];
    int j = (id < kNLG) ? id : id - kNLG;
    const float* hs = hprev + (size_t)lg_map[id] * D;
    const float* ev = eprev + (size_t)j * D;
#pragma unroll
    for (int q = 0; q < 5; ++q) {
      int d = lane + q * 64;
      if (d < D) acc[q] += hs[d] + ev[d];
    }
  }
  GATHER_TAIL(out)
}

// line graph, layer 0: ea from tables indexed by x[map2[k]]
__global__ void k_gather_lg0(const float* __restrict__ eprev, const int* __restrict__ src,
                             const int* __restrict__ map2, const int* __restrict__ x,
                             const float* __restrict__ emb1, const float* __restrict__ emb2,
                             const int* __restrict__ offs, const int* __restrict__ perm,
                             short* __restrict__ out) {
  GATHER_HEAD(kNLG)
#pragma unroll
  for (int q = 0; q < 5; ++q) {
    int d = lane + q * 64;
    acc[q] = (d < D) ? eprev[(size_t)node * D + d] + emb1[119 * D + d] + emb2[d] : 0.f;
  }
  int p1 = offs[node + 1];
  for (int p = offs[node]; p < p1; ++p) {
    int k = perm[p];
    int a = map2[k];
    const float* es = eprev + (size_t)src[k] * D;
    const float* e1 = emb1 + (size_t)x[2 * a] * D;
    const float* e2 = emb2 + (size_t)x[2 * a + 1] * D;
#pragma unroll
    for (int q = 0; q < 5; ++q) {
      int d = lane + q * 64;
      if (d < D) acc[q] += es[d] + e1[d] + e2[d];
    }
  }
  GATHER_TAIL(out)
}

// line graph, layers >0: ea = hprev[map2[k]]
__global__ void k_gather_lgL(const float* __restrict__ eprev, const float* __restrict__ hprev,
                             const int* __restrict__ src, const int* __restrict__ map2,
                             const float* __restrict__ emb1, const float* __restrict__ emb2,
                             const int* __restrict__ offs, const int* __restrict__ perm,
                             short* __restrict__ out) {
  GATHER_HEAD(kNLG)
#pragma unroll
  for (int q = 0; q < 5; ++q) {
    int d = lane + q * 64;
    acc[q] = (d < D) ? eprev[(size_t)node * D + d] + emb1[119 * D + d] + emb2[d] : 0.f;
  }
  int p1 = offs[node + 1];
  for (int p = offs[node]; p < p1; ++p) {
    int k = perm[p];
    const float* es = eprev + (size_t)src[k] * D;
    const float* ha = hprev + (size_t)map2[k] * D;
#pragma unroll
    for (int q = 0; q < 5; ++q) {
      int d = lane + q * 64;
      if (d < D) acc[q] += es[d] + ha[d];
    }
  }
  GATHER_TAIL(out)
}

// ---------------- misc elementwise ----------------

__global__ void k_embed_pair(const int* __restrict__ idx, const float* __restrict__ t1,
                             const float* __restrict__ t2, float* __restrict__ out, int n) {
  int g = blockIdx.x * blockDim.x + threadIdx.x;
  if (g >= n * D) return;
  int i = g / D, d = g - i * D;
  out[g] = t1[idx[2 * i] * D + d] + t2[idx[2 * i + 1] * D + d];
}

// W fp32 [Lc][K][N] -> Wt fp16 [Lc][Npad][Kpad] transposed, zero-padded
__global__ void k_convert_wt(const float* __restrict__ W, short* __restrict__ Wt,
                             int Lc, int K, int Nn, int Kpad, int Npad) {
  int g = blockIdx.x * blockDim.x + threadIdx.x;
  int per = Npad * Kpad;
  if (g >= Lc * per) return;
  int l = g / per, rem = g - l * per;
  int n = rem / Kpad, k = rem - n * Kpad;
  float v = (n < Nn && k < K) ? W[(size_t)l * K * Nn + (size_t)k * Nn + n] : 0.f;
  Wt[g] = f2h(v);
}

// ---------------- MFMA GEMM (fp16 inputs, fp32 accumulate) ----------------

template<bool RELU, bool OUT_F16>
__global__ __launch_bounds__(256) void k_mfma_gemm(
    const short* __restrict__ A, const short* __restrict__ Bt,
    const float* __restrict__ bias, int biasN,
    void* __restrict__ Cv, int Crows, int Ccols, int Cstride, int Kpad) {
  __shared__ __align__(16) short ldsA[128 * 32];
  __shared__ __align__(16) short ldsB[128 * 32];
  const int tid = threadIdx.x;
  const int lane = tid & 63, w = tid >> 6;
  const int brow = blockIdx.y * 128;
  const int bcol = blockIdx.x * 128;
  const int wr = w >> 1, wc = w & 1;

  f32x4 acc[4][4] = {};

  const int sr = tid >> 2;
  const int sc = (tid & 3) * 8;
  char* la = (char*)ldsA + w * 1024;
  char* lb = (char*)ldsB + w * 1024;

  for (int k0 = 0; k0 < Kpad; k0 += 32) {
    __syncthreads();
    const short* gA0 = A + (size_t)(brow + sr) * Kpad + (k0 + sc);
    const short* gB0 = Bt + (size_t)(bcol + sr) * Kpad + (k0 + sc);
    gload_lds16(gA0, la);
    gload_lds16(gA0 + (size_t)64 * Kpad, la + 4096);
    gload_lds16(gB0, lb);
    gload_lds16(gB0 + (size_t)64 * Kpad, lb + 4096);
    __syncthreads();

    const int kq = (lane >> 4) * 16;
    half8 af[4], bf[4];
#pragma unroll
    for (int m = 0; m < 4; ++m) {
      int row = wr * 64 + m * 16 + (lane & 15);
      af[m] = *(const half8*)((const char*)ldsA + row * 64 + kq);
    }
#pragma unroll
    for (int n = 0; n < 4; ++n) {
      int col = wc * 64 + n * 16 + (lane & 15);
      bf[n] = *(const half8*)((const char*)ldsB + col * 64 + kq);
    }
#pragma unroll
    for (int m = 0; m < 4; ++m)
#pragma unroll
      for (int n = 0; n < 4; ++n)
        acc[m][n] = __builtin_amdgcn_mfma_f32_16x16x32_f16(af[m], bf[n], acc[m][n], 0, 0, 0);
  }

  const int r0 = brow + wr * 64;
  const int c0 = bcol + wc * 64;
#pragma unroll
  for (int m = 0; m < 4; ++m) {
#pragma unroll
    for (int i = 0; i < 4; ++i) {
      int row = r0 + m * 16 + (lane >> 4) * 4 + i;
      if (row >= Crows) continue;
#pragma unroll
      for (int n = 0; n < 4; ++n) {
        int col = c0 + n * 16 + (lane & 15);
        if (col >= Ccols) continue;
        float b = (col < biasN) ? bias[col] : 0.f;
        float v = acc[m][n][i] + b;
        if (RELU) v = fmaxf(v, 0.f);
        if (OUT_F16)
          ((short*)Cv)[(size_t)row * Cstride + col] = f2h(v);
        else
          ((float*)Cv)[(size_t)row * Cstride + col] = v;
      }
    }
  }
}

// ---------------- batchnorm ----------------

__global__ void k_zero(float* __restrict__ p, int n) {
  int g = blockIdx.x * blockDim.x + threadIdx.x;
  if (g < n) p[g] = 0.f;
}

__global__ void k_bn_stats(const float* __restrict__ X, int n,
                           float* __restrict__ sums, float* __restrict__ sumsq) {
  int tid = threadIdx.x;
  int c0 = tid, c1 = tid + 256;
  float s0 = 0.f, q0 = 0.f, s1 = 0.f, q1 = 0.f;
  int rpb = (n + gridDim.x - 1) / gridDim.x;
  int r0 = blockIdx.x * rpb;
  int r1 = min(n, r0 + rpb);
  for (int r = r0; r < r1; ++r) {
    float v0 = X[r * D + c0];
    s0 += v0; q0 += v0 * v0;
    if (c1 < D) {
      float v1 = X[r * D + c1];
      s1 += v1; q1 += v1 * v1;
    }
  }
  atomicAdd(&sums[c0], s0);
  atomicAdd(&sumsq[c0], q0);
  if (c1 < D) {
    atomicAdd(&sums[c1], s1);
    atomicAdd(&sumsq[c1], q1);
  }
}

__global__ void k_bn_apply(float* __restrict__ X, int n, const float* __restrict__ sums,
                           const float* __restrict__ sumsq, const float* __restrict__ gamma,
                           const float* __restrict__ beta, int relu) {
  int g = blockIdx.x * blockDim.x + threadIdx.x;
  if (g >= n * D) return;
  int c = g % D;
  float inv_n = 1.f / (float)n;
  float mu = sums[c] * inv_n;
  float var = sumsq[c] * inv_n - mu * mu;
  float rs = rsqrtf(var + 1e-5f);
  float v = (X[g] - mu) * rs * gamma[c] + beta[c];
  if (relu) v = fmaxf(v, 0.f);
  X[g] = v;
}

}  // namespace

extern "C" void kernel_launch(void* const* d_in, const int* in_sizes, int n_in,
                              void* d_out_v, int out_size, void* d_ws, size_t ws_size,
                              hipStream_t stream) {
  const int*   x            = (const int*)d_in[0];
  const int*   edge_index   = (const int*)d_in[1];
  const int*   edge_attr    = (const int*)d_in[2];
  const int*   lg_x         = (const int*)d_in[3];
  const int*   lg_edge_index= (const int*)d_in[4];
  const int*   lg_map       = (const int*)d_in[5];
  const int*   lg_map2      = (const int*)d_in[6];
  const float* node_emb1    = (const float*)d_in[7];
  const float* node_emb2    = (const float*)d_in[8];
  const float* gnn_e_emb1   = (const float*)d_in[9];
  const float* gnn_e_emb2   = (const float*)d_in[10];
  const float* g_emb1       = (const float*)d_in[11];
  const float* g_emb2       = (const float*)d_in[12];
  const float* g_w1         = (const float*)d_in[13];
  const float* g_b1         = (const float*)d_in[14];
  const float* g_w2         = (const float*)d_in[15];
  const float* g_b2         = (const float*)d_in[16];
  const float* g_gamma      = (const float*)d_in[17];
  const float* g_beta       = (const float*)d_in[18];
  const float* lg_emb1      = (const float*)d_in[19];
  const float* lg_emb2      = (const float*)d_in[20];
  const float* lg_w1        = (const float*)d_in[21];
  const float* lg_b1        = (const float*)d_in[22];
  const float* lg_w2        = (const float*)d_in[23];
  const float* lg_b2        = (const float*)d_in[24];
  const float* lg_gamma     = (const float*)d_in[25];
  const float* lg_beta      = (const float*)d_in[26];

  float* out = (float*)d_out_v;
  char*  ws  = (char*)d_ws;

  size_t off = 0;
  auto alloc = [&](size_t bytes) { void* p = ws + off; off = (off + bytes + 255) & ~(size_t)255; return p; };
  short* main_ab = (short*)alloc((size_t)MP_N * K1P * 2);        // 12.9 MB
  short* lg_ab   = (short*)alloc((size_t)MP_NLG * K1P * 2);      // 25.6 MB
  short* hidden  = (short*)alloc((size_t)MP_NLG * N1P * 2);      // 51.3 MB
  short* g_w1t   = (short*)alloc((size_t)kL * N1P * K1P * 2);
  short* g_w2t   = (short*)alloc((size_t)kL * N2P * K2P * 2);
  short* lg_w1t  = (short*)alloc((size_t)kL * N1P * K1P * 2);
  short* lg_w2t  = (short*)alloc((size_t)kL * N2P * K2P * 2);
  float* stats   = (float*)alloc(600 * 4);
  // CSR arrays
  int* m0_offs = (int*)alloc((kN + 1) * 4);
  int* m0_cur  = (int*)alloc(kN * 4);
  int* m0_perm = (int*)alloc(kE * 4);
  int* mL_offs = (int*)alloc((kN + 1) * 4);
  int* mL_cur  = (int*)alloc(kN * 4);
  int* mL_perm = (int*)alloc(2 * kNLG * 4);
  int* lg_offs = (int*)alloc((kNLG + 1) * 4);
  int* lg_cur  = (int*)alloc(kNLG * 4);
  int* lg_perm = (int*)alloc(kELG * 4);

  auto hptr = [&](int l) { return out + (size_t)l * 60000 * D; };
  auto eptr = [&](int l) { return out + ((size_t)l * 60000 + kN) * D; };

  dim3 b(256);

  // ---- CSR build (once; graphs constant across layers) ----
  k_zero_int<<<(kN + 255) / 256, b, 0, stream>>>(m0_cur, kN);
  k_zero_int<<<(kN + 255) / 256, b, 0, stream>>>(mL_cur, kN);
  k_zero_int<<<(kNLG + 255) / 256, b, 0, stream>>>(lg_cur, kNLG);
  k_hist<<<(kE + 255) / 256, b, 0, stream>>>(edge_index + kE, kE, m0_cur);
  k_hist<<<(kNLG + 255) / 256, b, 0, stream>>>(lg_map + kNLG, kNLG, mL_cur);
  k_hist<<<(kNLG + 255) / 256, b, 0, stream>>>(lg_map, kNLG, mL_cur);
  k_hist<<<(kELG + 255) / 256, b, 0, stream>>>(lg_edge_index + kELG, kELG, lg_cur);
  k_scan<<<1, b, 0, stream>>>(m0_cur, m0_offs, kN);
  k_scan<<<1, b, 0, stream>>>(mL_cur, mL_offs, kN);
  k_scan<<<1, b, 0, stream>>>(lg_cur, lg_offs, kNLG);
  k_fill<<<(kE + 255) / 256, b, 0, stream>>>(edge_index + kE, kE, 0, m0_cur, m0_perm);
  k_fill<<<(kNLG + 255) / 256, b, 0, stream>>>(lg_map + kNLG, kNLG, 0, mL_cur, mL_perm);
  k_fill<<<(kNLG + 255) / 256, b, 0, stream>>>(lg_map, kNLG, kNLG, mL_cur, mL_perm);
  k_fill<<<(kELG + 255) / 256, b, 0, stream>>>(lg_edge_index + kELG, kELG, 0, lg_cur, lg_perm);

  // ---- weights + pad-row zeroing ----
  {
    int tot1 = kL * N1P * K1P, tot2 = kL * N2P * K2P;
    k_convert_wt<<<(tot1 + 255) / 256, b, 0, stream>>>(g_w1, g_w1t, kL, D, 2 * D, K1P, N1P);
    k_convert_wt<<<(tot2 + 255) / 256, b, 0, stream>>>(g_w2, g_w2t, kL, 2 * D, D, K2P, N2P);
    k_convert_wt<<<(tot1 + 255) / 256, b, 0, stream>>>(lg_w1, lg_w1t, kL, D, 2 * D, K1P, N1P);
    k_convert_wt<<<(tot2 + 255) / 256, b, 0, stream>>>(lg_w2, lg_w2t, kL, 2 * D, D, K2P, N2P);
    k_zero_short<<<((MP_N - kN) * K1P + 255) / 256, b, 0, stream>>>(
        main_ab + (size_t)kN * K1P, (MP_N - kN) * K1P);
    k_zero_short<<<((MP_NLG - kNLG) * K1P + 255) / 256, b, 0, stream>>>(
        lg_ab + (size_t)kNLG * K1P, (MP_NLG - kNLG) * K1P);
  }

  k_embed_pair<<<(kN * D + 255) / 256, b, 0, stream>>>(x, node_emb1, node_emb2, hptr(0), kN);
  k_embed_pair<<<(kNLG * D + 255) / 256, b, 0, stream>>>(lg_x, gnn_e_emb1, gnn_e_emb2, eptr(0), kNLG);

  for (int l = 0; l < kL; ++l) {
    const float* ge1 = g_emb1 + (size_t)l * 6 * D;
    const float* ge2 = g_emb2 + (size_t)l * 3 * D;
    const float* le1 = lg_emb1 + (size_t)l * 120 * D;
    const float* le2 = lg_emb2 + (size_t)l * 3 * D;
    float* hprev = hptr(l);
    float* eprev = eptr(l);
    float* hcur  = hptr(l + 1);
    float* ecur  = eptr(l + 1);
    int relu_tail = (l < kL - 1) ? 1 : 0;

    // -------- main-graph GINConv (M = 20000) --------
    {
      const int M = kN, mt = MP_N / 128;
      if (l == 0)
        k_gather_m0<<<(M + 3) / 4, b, 0, stream>>>(hprev, edge_index, edge_attr, ge1, ge2,
                                                   m0_offs, m0_perm, main_ab);
      else
        k_gather_mL<<<(M + 3) / 4, b, 0, stream>>>(hprev, eprev, lg_map, ge1, ge2,
                                                   mL_offs, mL_perm, main_ab);
      k_mfma_gemm<true, true><<<dim3(N1P / 128, mt), b, 0, stream>>>(
          main_ab, g_w1t + (size_t)l * N1P * K1P, g_b1 + (size_t)l * 2 * D, 2 * D,
          hidden, MP_N, N1P, N1P, K1P);
      k_mfma_gemm<false, false><<<dim3(N2P / 128, mt), b, 0, stream>>>(
          hidden, g_w2t + (size_t)l * N2P * K2P, g_b2 + (size_t)l * D, D,
          hcur, M, D, D, K2P);
      k_zero<<<3, b, 0, stream>>>(stats, 2 * D);
      k_bn_stats<<<256, b, 0, stream>>>(hcur, M, stats, stats + D);
      k_bn_apply<<<(M * D + 255) / 256, b, 0, stream>>>(hcur, M, stats, stats + D,
                                                        g_gamma + (size_t)l * D,
                                                        g_beta + (size_t)l * D, relu_tail);
    }

    // -------- line-graph GINConv (M = 40000) --------
    {
      const int M = kNLG, mt = MP_NLG / 128;
      if (l == 0)
        k_gather_lg0<<<(M + 3) / 4, b, 0, stream>>>(eprev, lg_edge_index, lg_map2, x,
                                                    le1, le2, lg_offs, lg_perm, lg_ab);
      else
        k_gather_lgL<<<(M + 3) / 4, b, 0, stream>>>(eprev, hprev, lg_edge_index, lg_map2,
                                                    le1, le2, lg_offs, lg_perm, lg_ab);
      k_mfma_gemm<true, true><<<dim3(N1P / 128, mt), b, 0, stream>>>(
          lg_ab, lg_w1t + (size_t)l * N1P * K1P, lg_b1 + (size_t)l * 2 * D, 2 * D,
          hidden, MP_NLG, N1P, N1P, K1P);
      k_mfma_gemm<false, false><<<dim3(N2P / 128, mt), b, 0, stream>>>(
          hidden, lg_w2t + (size_t)l * N2P * K2P, lg_b2 + (size_t)l * D, D,
          ecur, M, D, D, K2P);
      k_zero<<<3, b, 0, stream>>>(stats, 2 * D);
      k_bn_stats<<<256, b, 0, stream>>>(ecur, M, stats, stats + D);
      k_bn_apply<<<(M * D + 255) / 256, b, 0, stream>>>(ecur, M, stats, stats + D,
                                                        lg_gamma + (size_t)l * D,
                                                        lg_beta + (size_t)l * D, relu_tail);
    }
  }
}

// Round 5
// 2099.123 us; speedup vs baseline: 3.3651x; 1.2444x over previous
//
#include <hip/hip_runtime.h>

#define D 300

namespace {

constexpr int kN   = 20000;
constexpr int kNLG = 40000;
constexpr int kE   = 80000;
constexpr int kELG = 200000;
constexpr int kL   = 5;

constexpr int K1P = 320;   // K=300 padded
constexpr int N1P = 640;   // N=600 padded
constexpr int K2P = 640;   // K=600 padded (hidden stride)
constexpr int N2P = 384;   // N=300 padded
constexpr int MP_N   = 20096;
constexpr int MP_NLG = 40064;
constexpr int RU = 150;    // uints per fp16 history row (300 fp16)

typedef __attribute__((ext_vector_type(8))) _Float16 half8;
typedef __attribute__((ext_vector_type(2))) _Float16 half2v;
typedef __attribute__((ext_vector_type(4))) float f32x4;

__device__ inline short f2h(float f) {
  _Float16 h = (_Float16)f;
  return __builtin_bit_cast(short, h);
}

__device__ inline float2 upk(unsigned u) {
  half2v h = __builtin_bit_cast(half2v, u);
  return make_float2((float)h.x, (float)h.y);
}

__device__ inline unsigned pk(float a, float b) {
  half2v h;
  h.x = (_Float16)a;
  h.y = (_Float16)b;
  return __builtin_bit_cast(unsigned, h);
}

__device__ inline void gload_lds16(const void* g, void* l) {
  __builtin_amdgcn_global_load_lds(
      (const __attribute__((address_space(1))) void*)g,
      (__attribute__((address_space(3))) void*)l, 16, 0, 0);
}

// ---------------- CSR build ----------------

__global__ void k_zero_int(int* __restrict__ p, int n) {
  int g = blockIdx.x * blockDim.x + threadIdx.x;
  if (g < n) p[g] = 0;
}

__global__ void k_zero_short(short* __restrict__ p, int n) {
  int g = blockIdx.x * blockDim.x + threadIdx.x;
  if (g < n) p[g] = 0;
}

__global__ void k_hist(const int* __restrict__ dst, int n, int* __restrict__ deg) {
  int g = blockIdx.x * blockDim.x + threadIdx.x;
  if (g < n) atomicAdd(&deg[dst[g]], 1);
}

__global__ __launch_bounds__(256) void k_scan(int* __restrict__ cursor,
                                              int* __restrict__ offs, int n) {
  __shared__ int part[256];
  int tid = threadIdx.x;
  int chunk = (n + 255) / 256;
  int s0 = tid * chunk;
  int s1 = min(n, s0 + chunk);
  int sum = 0;
  for (int i = s0; i < s1; ++i) sum += cursor[i];
  part[tid] = sum;
  __syncthreads();
  for (int off = 1; off < 256; off <<= 1) {
    int v = (tid >= off) ? part[tid - off] : 0;
    __syncthreads();
    part[tid] += v;
    __syncthreads();
  }
  int run = (tid == 0) ? 0 : part[tid - 1];
  for (int i = s0; i < s1; ++i) {
    int dv = cursor[i];
    offs[i] = run;
    cursor[i] = run;
    run += dv;
  }
  if (tid == 255) offs[n] = run;
}

__global__ void k_fill(const int* __restrict__ dst, int n, int idbase,
                       int* __restrict__ cursor, int* __restrict__ perm) {
  int g = blockIdx.x * blockDim.x + threadIdx.x;
  if (g < n) {
    int pos = atomicAdd(&cursor[dst[g]], 1);
    perm[pos] = idbase + g;
  }
}

// ---------------- fused gather kernels (CSR, fp16 history reads) ----------------
// one 64-lane wave per dst node; packed 2xfp16 per lane; writes fp16 GEMM-A row

__global__ void k_gather_m0(const unsigned* __restrict__ h16, const int* __restrict__ src,
                            const int* __restrict__ eattr, const float* __restrict__ emb1,
                            const float* __restrict__ emb2, const int* __restrict__ offs,
                            const int* __restrict__ perm, unsigned* __restrict__ outp) {
  int node = blockIdx.x * 4 + (threadIdx.x >> 6);
  int lane = threadIdx.x & 63;
  if (node >= kN) return;
  float sx[3], sy[3];
  const unsigned* hn = h16 + (size_t)node * RU;
#pragma unroll
  for (int q = 0; q < 3; ++q) {
    int u = lane + q * 64;
    if (u < RU) {
      float2 t = upk(hn[u]);
      sx[q] = t.x + emb1[4 * D + 2 * u] + emb2[2 * u];
      sy[q] = t.y + emb1[4 * D + 2 * u + 1] + emb2[2 * u + 1];
    } else { sx[q] = sy[q] = 0.f; }
  }
  int p1 = offs[node + 1];
  for (int p = offs[node]; p < p1; ++p) {
    int k = perm[p];
    const unsigned* hs = h16 + (size_t)src[k] * RU;
    const float* e1 = emb1 + (size_t)eattr[2 * k] * D;
    const float* e2 = emb2 + (size_t)eattr[2 * k + 1] * D;
#pragma unroll
    for (int q = 0; q < 3; ++q) {
      int u = lane + q * 64;
      if (u < RU) {
        float2 a = upk(hs[u]);
        sx[q] += a.x + e1[2 * u] + e2[2 * u];
        sy[q] += a.y + e1[2 * u + 1] + e2[2 * u + 1];
      }
    }
  }
  unsigned* orow = outp + (size_t)node * (K1P / 2);
#pragma unroll
  for (int q = 0; q < 3; ++q) {
    int u = lane + q * 64;
    if (u < RU) orow[u] = pk(sx[q], sy[q]);
    else if (u < K1P / 2) orow[u] = 0;
  }
}

__global__ void k_gather_mL(const unsigned* __restrict__ h16, const unsigned* __restrict__ e16,
                            const int* __restrict__ lg_map, const float* __restrict__ emb1,
                            const float* __restrict__ emb2, const int* __restrict__ offs,
                            const int* __restrict__ perm, unsigned* __restrict__ outp) {
  int node = blockIdx.x * 4 + (threadIdx.x >> 6);
  int lane = threadIdx.x & 63;
  if (node >= kN) return;
  float sx[3], sy[3];
  const unsigned* hn = h16 + (size_t)node * RU;
#pragma unroll
  for (int q = 0; q < 3; ++q) {
    int u = lane + q * 64;
    if (u < RU) {
      float2 t = upk(hn[u]);
      sx[q] = t.x + emb1[4 * D + 2 * u] + emb2[2 * u];
      sy[q] = t.y + emb1[4 * D + 2 * u + 1] + emb2[2 * u + 1];
    } else { sx[q] = sy[q] = 0.f; }
  }
  int p1 = offs[node + 1];
  for (int p = offs[node]; p < p1; ++p) {
    int id = perm[p];
    int j = (id < kNLG) ? id : id - kNLG;
    const unsigned* hs = h16 + (size_t)lg_map[id] * RU;
    const unsigned* ev = e16 + (size_t)j * RU;
#pragma unroll
    for (int q = 0; q < 3; ++q) {
      int u = lane + q * 64;
      if (u < RU) {
        float2 a = upk(hs[u]), b2 = upk(ev[u]);
        sx[q] += a.x + b2.x;
        sy[q] += a.y + b2.y;
      }
    }
  }
  unsigned* orow = outp + (size_t)node * (K1P / 2);
#pragma unroll
  for (int q = 0; q < 3; ++q) {
    int u = lane + q * 64;
    if (u < RU) orow[u] = pk(sx[q], sy[q]);
    else if (u < K1P / 2) orow[u] = 0;
  }
}

__global__ void k_gather_lg0(const unsigned* __restrict__ e16, const int* __restrict__ src,
                             const int* __restrict__ map2, const int* __restrict__ x,
                             const float* __restrict__ emb1, const float* __restrict__ emb2,
                             const int* __restrict__ offs, const int* __restrict__ perm,
                             unsigned* __restrict__ outp) {
  int node = blockIdx.x * 4 + (threadIdx.x >> 6);
  int lane = threadIdx.x & 63;
  if (node >= kNLG) return;
  float sx[3], sy[3];
  const unsigned* en = e16 + (size_t)node * RU;
#pragma unroll
  for (int q = 0; q < 3; ++q) {
    int u = lane + q * 64;
    if (u < RU) {
      float2 t = upk(en[u]);
      sx[q] = t.x + emb1[119 * D + 2 * u] + emb2[2 * u];
      sy[q] = t.y + emb1[119 * D + 2 * u + 1] + emb2[2 * u + 1];
    } else { sx[q] = sy[q] = 0.f; }
  }
  int p1 = offs[node + 1];
  for (int p = offs[node]; p < p1; ++p) {
    int k = perm[p];
    int a = map2[k];
    const unsigned* es = e16 + (size_t)src[k] * RU;
    const float* e1 = emb1 + (size_t)x[2 * a] * D;
    const float* e2 = emb2 + (size_t)x[2 * a + 1] * D;
#pragma unroll
    for (int q = 0; q < 3; ++q) {
      int u = lane + q * 64;
      if (u < RU) {
        float2 av = upk(es[u]);
        sx[q] += av.x + e1[2 * u] + e2[2 * u];
        sy[q] += av.y + e1[2 * u + 1] + e2[2 * u + 1];
      }
    }
  }
  unsigned* orow = outp + (size_t)node * (K1P / 2);
#pragma unroll
  for (int q = 0; q < 3; ++q) {
    int u = lane + q * 64;
    if (u < RU) orow[u] = pk(sx[q], sy[q]);
    else if (u < K1P / 2) orow[u] = 0;
  }
}

__global__ void k_gather_lgL(const unsigned* __restrict__ e16, const unsigned* __restrict__ h16,
                             const int* __restrict__ src, const int* __restrict__ map2,
                             const float* __restrict__ emb1, const float* __restrict__ emb2,
                             const int* __restrict__ offs, const int* __restrict__ perm,
                             unsigned* __restrict__ outp) {
  int node = blockIdx.x * 4 + (threadIdx.x >> 6);
  int lane = threadIdx.x & 63;
  if (node >= kNLG) return;
  float sx[3], sy[3];
  const unsigned* en = e16 + (size_t)node * RU;
#pragma unroll
  for (int q = 0; q < 3; ++q) {
    int u = lane + q * 64;
    if (u < RU) {
      float2 t = upk(en[u]);
      sx[q] = t.x + emb1[119 * D + 2 * u] + emb2[2 * u];
      sy[q] = t.y + emb1[119 * D + 2 * u + 1] + emb2[2 * u + 1];
    } else { sx[q] = sy[q] = 0.f; }
  }
  int p1 = offs[node + 1];
  for (int p = offs[node]; p < p1; ++p) {
    int k = perm[p];
    const unsigned* es = e16 + (size_t)src[k] * RU;
    const unsigned* ha = h16 + (size_t)map2[k] * RU;
#pragma unroll
    for (int q = 0; q < 3; ++q) {
      int u = lane + q * 64;
      if (u < RU) {
        float2 a = upk(es[u]), b2 = upk(ha[u]);
        sx[q] += a.x + b2.x;
        sy[q] += a.y + b2.y;
      }
    }
  }
  unsigned* orow = outp + (size_t)node * (K1P / 2);
#pragma unroll
  for (int q = 0; q < 3; ++q) {
    int u = lane + q * 64;
    if (u < RU) orow[u] = pk(sx[q], sy[q]);
    else if (u < K1P / 2) orow[u] = 0;
  }
}

// ---------------- misc elementwise ----------------

__global__ void k_embed_pair(const int* __restrict__ idx, const float* __restrict__ t1,
                             const float* __restrict__ t2, float* __restrict__ out,
                             short* __restrict__ hist, int n) {
  int g = blockIdx.x * blockDim.x + threadIdx.x;
  if (g >= n * D) return;
  int i = g / D, d = g - i * D;
  float v = t1[idx[2 * i] * D + d] + t2[idx[2 * i + 1] * D + d];
  out[g] = v;
  hist[g] = f2h(v);
}

__global__ void k_convert_wt(const float* __restrict__ W, short* __restrict__ Wt,
                             int Lc, int K, int Nn, int Kpad, int Npad) {
  int g = blockIdx.x * blockDim.x + threadIdx.x;
  int per = Npad * Kpad;
  if (g >= Lc * per) return;
  int l = g / per, rem = g - l * per;
  int n = rem / Kpad, k = rem - n * Kpad;
  float v = (n < Nn && k < K) ? W[(size_t)l * K * Nn + (size_t)k * Nn + n] : 0.f;
  Wt[g] = f2h(v);
}

// ---------------- MFMA GEMM (fp16 in, fp32 acc; optional fused BN stats) ----------------

template<bool RELU, bool OUT_F16, bool STATS>
__global__ __launch_bounds__(256) void k_mfma_gemm(
    const short* __restrict__ A, const short* __restrict__ Bt,
    const float* __restrict__ bias, int biasN,
    void* __restrict__ Cv, int Crows, int Ccols, int Cstride, int Kpad,
    float* __restrict__ gsum, float* __restrict__ gsq) {
  __shared__ __align__(16) short ldsA[128 * 32];
  __shared__ __align__(16) short ldsB[128 * 32];
  __shared__ float sd[256];  // [0:128) col sums, [128:256) col sumsq
  const int tid = threadIdx.x;
  const int lane = tid & 63, w = tid >> 6;
  const int brow = blockIdx.y * 128;
  const int bcol = blockIdx.x * 128;
  const int wr = w >> 1, wc = w & 1;

  if (STATS) sd[tid] = 0.f;

  f32x4 acc[4][4] = {};

  const int sr = tid >> 2;
  const int sc = (tid & 3) * 8;
  char* la = (char*)ldsA + w * 1024;
  char* lb = (char*)ldsB + w * 1024;

  for (int k0 = 0; k0 < Kpad; k0 += 32) {
    __syncthreads();
    const short* gA0 = A + (size_t)(brow + sr) * Kpad + (k0 + sc);
    const short* gB0 = Bt + (size_t)(bcol + sr) * Kpad + (k0 + sc);
    gload_lds16(gA0, la);
    gload_lds16(gA0 + (size_t)64 * Kpad, la + 4096);
    gload_lds16(gB0, lb);
    gload_lds16(gB0 + (size_t)64 * Kpad, lb + 4096);
    __syncthreads();

    const int kq = (lane >> 4) * 16;
    half8 af[4], bf[4];
#pragma unroll
    for (int m = 0; m < 4; ++m) {
      int row = wr * 64 + m * 16 + (lane & 15);
      af[m] = *(const half8*)((const char*)ldsA + row * 64 + kq);
    }
#pragma unroll
    for (int n = 0; n < 4; ++n) {
      int col = wc * 64 + n * 16 + (lane & 15);
      bf[n] = *(const half8*)((const char*)ldsB + col * 64 + kq);
    }
#pragma unroll
    for (int m = 0; m < 4; ++m)
#pragma unroll
      for (int n = 0; n < 4; ++n)
        acc[m][n] = __builtin_amdgcn_mfma_f32_16x16x32_f16(af[m], bf[n], acc[m][n], 0, 0, 0);
  }

  const int r0 = brow + wr * 64;
  const int c0 = bcol + wc * 64;
  float ps[4] = {}, pq[4] = {};
#pragma unroll
  for (int m = 0; m < 4; ++m) {
#pragma unroll
    for (int i = 0; i < 4; ++i) {
      int row = r0 + m * 16 + (lane >> 4) * 4 + i;
      bool rv = row < Crows;
#pragma unroll
      for (int n = 0; n < 4; ++n) {
        int col = c0 + n * 16 + (lane & 15);
        float bv = (col < biasN) ? bias[col] : 0.f;
        float v = acc[m][n][i] + bv;
        if (RELU) v = fmaxf(v, 0.f);
        if (rv && col < Ccols) {
          if (OUT_F16)
            ((short*)Cv)[(size_t)row * Cstride + col] = f2h(v);
          else
            ((float*)Cv)[(size_t)row * Cstride + col] = v;
          if (STATS) { ps[n] += v; pq[n] += v * v; }
        }
      }
    }
  }

  if (STATS) {
#pragma unroll
    for (int n = 0; n < 4; ++n) {
      float s = ps[n], q = pq[n];
      s += __shfl_xor(s, 16); q += __shfl_xor(q, 16);
      s += __shfl_xor(s, 32); q += __shfl_xor(q, 32);
      if ((lane >> 4) == 0) {
        int c = wc * 64 + n * 16 + (lane & 15);
        atomicAdd(&sd[c], s);
        atomicAdd(&sd[128 + c], q);
      }
    }
    __syncthreads();
    if (tid < 128) {
      int col = bcol + tid;
      if (col < Ccols) {
        atomicAdd(&gsum[col], sd[tid]);
        atomicAdd(&gsq[col], sd[128 + tid]);
      }
    }
  }
}

// ---------------- batchnorm apply (stats precomputed in GEMM2) ----------------

__global__ void k_zero(float* __restrict__ p, int n) {
  int g = blockIdx.x * blockDim.x + threadIdx.x;
  if (g < n) p[g] = 0.f;
}

__global__ void k_bn_apply(float* __restrict__ X, short* __restrict__ hist, int n,
                           const float* __restrict__ sums, const float* __restrict__ sumsq,
                           const float* __restrict__ gamma, const float* __restrict__ beta,
                           int relu) {
  int g = blockIdx.x * blockDim.x + threadIdx.x;
  if (g >= n * D) return;
  int c = g % D;
  float inv_n = 1.f / (float)n;
  float mu = sums[c] * inv_n;
  float var = sumsq[c] * inv_n - mu * mu;
  float rs = rsqrtf(var + 1e-5f);
  float v = (X[g] - mu) * rs * gamma[c] + beta[c];
  if (relu) v = fmaxf(v, 0.f);
  X[g] = v;
  hist[g] = f2h(v);
}

}  // namespace

extern "C" void kernel_launch(void* const* d_in, const int* in_sizes, int n_in,
                              void* d_out_v, int out_size, void* d_ws, size_t ws_size,
                              hipStream_t stream) {
  const int*   x            = (const int*)d_in[0];
  const int*   edge_index   = (const int*)d_in[1];
  const int*   edge_attr    = (const int*)d_in[2];
  const int*   lg_x         = (const int*)d_in[3];
  const int*   lg_edge_index= (const int*)d_in[4];
  const int*   lg_map       = (const int*)d_in[5];
  const int*   lg_map2      = (const int*)d_in[6];
  const float* node_emb1    = (const float*)d_in[7];
  const float* node_emb2    = (const float*)d_in[8];
  const float* gnn_e_emb1   = (const float*)d_in[9];
  const float* gnn_e_emb2   = (const float*)d_in[10];
  const float* g_emb1       = (const float*)d_in[11];
  const float* g_emb2       = (const float*)d_in[12];
  const float* g_w1         = (const float*)d_in[13];
  const float* g_b1         = (const float*)d_in[14];
  const float* g_w2         = (const float*)d_in[15];
  const float* g_b2         = (const float*)d_in[16];
  const float* g_gamma      = (const float*)d_in[17];
  const float* g_beta       = (const float*)d_in[18];
  const float* lg_emb1      = (const float*)d_in[19];
  const float* lg_emb2      = (const float*)d_in[20];
  const float* lg_w1        = (const float*)d_in[21];
  const float* lg_b1        = (const float*)d_in[22];
  const float* lg_w2        = (const float*)d_in[23];
  const float* lg_b2        = (const float*)d_in[24];
  const float* lg_gamma     = (const float*)d_in[25];
  const float* lg_beta      = (const float*)d_in[26];

  float* out = (float*)d_out_v;
  char*  ws  = (char*)d_ws;

  size_t off = 0;
  auto alloc = [&](size_t bytes) { void* p = ws + off; off = (off + bytes + 255) & ~(size_t)255; return p; };
  short* main_ab = (short*)alloc((size_t)MP_N * K1P * 2);
  short* lg_ab   = (short*)alloc((size_t)MP_NLG * K1P * 2);
  short* hidden  = (short*)alloc((size_t)MP_NLG * N1P * 2);
  short* hist16  = (short*)alloc((size_t)(kL + 1) * 60000 * D * 2);  // fp16 h/e history, 216 MB
  short* g_w1t   = (short*)alloc((size_t)kL * N1P * K1P * 2);
  short* g_w2t   = (short*)alloc((size_t)kL * N2P * K2P * 2);
  short* lg_w1t  = (short*)alloc((size_t)kL * N1P * K1P * 2);
  short* lg_w2t  = (short*)alloc((size_t)kL * N2P * K2P * 2);
  float* stats   = (float*)alloc(600 * 4);
  int* m0_offs = (int*)alloc((kN + 1) * 4);
  int* m0_cur  = (int*)alloc(kN * 4);
  int* m0_perm = (int*)alloc(kE * 4);
  int* mL_offs = (int*)alloc((kN + 1) * 4);
  int* mL_cur  = (int*)alloc(kN * 4);
  int* mL_perm = (int*)alloc(2 * kNLG * 4);
  int* lg_offs = (int*)alloc((kNLG + 1) * 4);
  int* lg_cur  = (int*)alloc(kNLG * 4);
  int* lg_perm = (int*)alloc(kELG * 4);

  auto hptr  = [&](int l) { return out + (size_t)l * 60000 * D; };
  auto eptr  = [&](int l) { return out + ((size_t)l * 60000 + kN) * D; };
  auto h16p  = [&](int l) { return hist16 + (size_t)l * 60000 * D; };
  auto e16p  = [&](int l) { return hist16 + ((size_t)l * 60000 + kN) * D; };

  dim3 b(256);

  // ---- CSR build ----
  k_zero_int<<<(kN + 255) / 256, b, 0, stream>>>(m0_cur, kN);
  k_zero_int<<<(kN + 255) / 256, b, 0, stream>>>(mL_cur, kN);
  k_zero_int<<<(kNLG + 255) / 256, b, 0, stream>>>(lg_cur, kNLG);
  k_hist<<<(kE + 255) / 256, b, 0, stream>>>(edge_index + kE, kE, m0_cur);
  k_hist<<<(kNLG + 255) / 256, b, 0, stream>>>(lg_map + kNLG, kNLG, mL_cur);
  k_hist<<<(kNLG + 255) / 256, b, 0, stream>>>(lg_map, kNLG, mL_cur);
  k_hist<<<(kELG + 255) / 256, b, 0, stream>>>(lg_edge_index + kELG, kELG, lg_cur);
  k_scan<<<1, b, 0, stream>>>(m0_cur, m0_offs, kN);
  k_scan<<<1, b, 0, stream>>>(mL_cur, mL_offs, kN);
  k_scan<<<1, b, 0, stream>>>(lg_cur, lg_offs, kNLG);
  k_fill<<<(kE + 255) / 256, b, 0, stream>>>(edge_index + kE, kE, 0, m0_cur, m0_perm);
  k_fill<<<(kNLG + 255) / 256, b, 0, stream>>>(lg_map + kNLG, kNLG, 0, mL_cur, mL_perm);
  k_fill<<<(kNLG + 255) / 256, b, 0, stream>>>(lg_map, kNLG, kNLG, mL_cur, mL_perm);
  k_fill<<<(kELG + 255) / 256, b, 0, stream>>>(lg_edge_index + kELG, kELG, 0, lg_cur, lg_perm);

  // ---- weights + pad-row zeroing ----
  {
    int tot1 = kL * N1P * K1P, tot2 = kL * N2P * K2P;
    k_convert_wt<<<(tot1 + 255) / 256, b, 0, stream>>>(g_w1, g_w1t, kL, D, 2 * D, K1P, N1P);
    k_convert_wt<<<(tot2 + 255) / 256, b, 0, stream>>>(g_w2, g_w2t, kL, 2 * D, D, K2P, N2P);
    k_convert_wt<<<(tot1 + 255) / 256, b, 0, stream>>>(lg_w1, lg_w1t, kL, D, 2 * D, K1P, N1P);
    k_convert_wt<<<(tot2 + 255) / 256, b, 0, stream>>>(lg_w2, lg_w2t, kL, 2 * D, D, K2P, N2P);
    k_zero_short<<<((MP_N - kN) * K1P + 255) / 256, b, 0, stream>>>(
        main_ab + (size_t)kN * K1P, (MP_N - kN) * K1P);
    k_zero_short<<<((MP_NLG - kNLG) * K1P + 255) / 256, b, 0, stream>>>(
        lg_ab + (size_t)kNLG * K1P, (MP_NLG - kNLG) * K1P);
  }

  k_embed_pair<<<(kN * D + 255) / 256, b, 0, stream>>>(x, node_emb1, node_emb2,
                                                       hptr(0), h16p(0), kN);
  k_embed_pair<<<(kNLG * D + 255) / 256, b, 0, stream>>>(lg_x, gnn_e_emb1, gnn_e_emb2,
                                                         eptr(0), e16p(0), kNLG);

  for (int l = 0; l < kL; ++l) {
    const float* ge1 = g_emb1 + (size_t)l * 6 * D;
    const float* ge2 = g_emb2 + (size_t)l * 3 * D;
    const float* le1 = lg_emb1 + (size_t)l * 120 * D;
    const float* le2 = lg_emb2 + (size_t)l * 3 * D;
    int relu_tail = (l < kL - 1) ? 1 : 0;

    // -------- main-graph GINConv (M = 20000) --------
    {
      const int M = kN, mt = MP_N / 128;
      if (l == 0)
        k_gather_m0<<<(M + 3) / 4, b, 0, stream>>>((const unsigned*)h16p(0), edge_index,
                                                   edge_attr, ge1, ge2, m0_offs, m0_perm,
                                                   (unsigned*)main_ab);
      else
        k_gather_mL<<<(M + 3) / 4, b, 0, stream>>>((const unsigned*)h16p(l),
                                                   (const unsigned*)e16p(l), lg_map, ge1, ge2,
                                                   mL_offs, mL_perm, (unsigned*)main_ab);
      k_mfma_gemm<true, true, false><<<dim3(N1P / 128, mt), b, 0, stream>>>(
          main_ab, g_w1t + (size_t)l * N1P * K1P, g_b1 + (size_t)l * 2 * D, 2 * D,
          hidden, MP_N, N1P, N1P, K1P, nullptr, nullptr);
      k_zero<<<3, b, 0, stream>>>(stats, 2 * D);
      k_mfma_gemm<false, false, true><<<dim3(N2P / 128, mt), b, 0, stream>>>(
          hidden, g_w2t + (size_t)l * N2P * K2P, g_b2 + (size_t)l * D, D,
          hptr(l + 1), M, D, D, K2P, stats, stats + D);
      k_bn_apply<<<(M * D + 255) / 256, b, 0, stream>>>(hptr(l + 1), h16p(l + 1), M,
                                                        stats, stats + D,
                                                        g_gamma + (size_t)l * D,
                                                        g_beta + (size_t)l * D, relu_tail);
    }

    // -------- line-graph GINConv (M = 40000) --------
    {
      const int M = kNLG, mt = MP_NLG / 128;
      if (l == 0)
        k_gather_lg0<<<(M + 3) / 4, b, 0, stream>>>((const unsigned*)e16p(0), lg_edge_index,
                                                    lg_map2, x, le1, le2, lg_offs, lg_perm,
                                                    (unsigned*)lg_ab);
      else
        k_gather_lgL<<<(M + 3) / 4, b, 0, stream>>>((const unsigned*)e16p(l),
                                                    (const unsigned*)h16p(l), lg_edge_index,
                                                    lg_map2, le1, le2, lg_offs, lg_perm,
                                                    (unsigned*)lg_ab);
      k_mfma_gemm<true, true, false><<<dim3(N1P / 128, mt), b, 0, stream>>>(
          lg_ab, lg_w1t + (size_t)l * N1P * K1P, lg_b1 + (size_t)l * 2 * D, 2 * D,
          hidden, MP_NLG, N1P, N1P, K1P, nullptr, nullptr);
      k_zero<<<3, b, 0, stream>>>(stats, 2 * D);
      k_mfma_gemm<false, false, true><<<dim3(N2P / 128, mt), b, 0, stream>>>(
          hidden, lg_w2t + (size_t)l * N2P * K2P, lg_b2 + (size_t)l * D, D,
          eptr(l + 1), M, D, D, K2P, stats, stats + D);
      k_bn_apply<<<(M * D + 255) / 256, b, 0, stream>>>(eptr(l + 1), e16p(l + 1), M,
                                                        stats, stats + D,
                                                        lg_gamma + (size_t)l * D,
                                                        lg_beta + (size_t)l * D, relu_tail);
    }
  }
}

// Round 7
// 1831.521 us; speedup vs baseline: 3.8568x; 1.1461x over previous
//
#include <hip/hip_runtime.h>

#define D 300

namespace {

constexpr int kN   = 20000;
constexpr int kNLG = 40000;
constexpr int kE   = 80000;
constexpr int kELG = 200000;
constexpr int kL   = 5;

constexpr int K1P = 320;
constexpr int N1P = 640;
constexpr int K2P = 640;
constexpr int N2P = 384;        // GEMM2 col tiles (300 padded to 3x128)
constexpr int MP_N   = 20096;   // main rows padded (157 tiles)
constexpr int MP_ALL = 60160;   // + 40064 lg rows (313 tiles) = 470 tiles
constexpr int MAIN_TILES = 157;
constexpr int RU = 150;         // uints per fp16 row (300 fp16)

typedef __attribute__((ext_vector_type(8))) _Float16 half8;
typedef __attribute__((ext_vector_type(2))) _Float16 half2v;
typedef __attribute__((ext_vector_type(4))) float f32x4;

__device__ inline short f2h(float f) {
  _Float16 h = (_Float16)f;
  return __builtin_bit_cast(short, h);
}

__device__ inline float2 upk(unsigned u) {
  half2v h = __builtin_bit_cast(half2v, u);
  return make_float2((float)h.x, (float)h.y);
}

__device__ inline unsigned pk(float a, float b) {
  half2v h;
  h.x = (_Float16)a;
  h.y = (_Float16)b;
  return __builtin_bit_cast(unsigned, h);
}

__device__ inline void gload_lds16(const void* g, void* l) {
  __builtin_amdgcn_global_load_lds(
      (const __attribute__((address_space(1))) void*)g,
      (__attribute__((address_space(3))) void*)l, 16, 0, 0);
}

// ---------------- init: zero stats + A-buffer pad rows ----------------

__global__ void k_init(float* __restrict__ stats, short* __restrict__ ab) {
  int g = blockIdx.x * blockDim.x + threadIdx.x;
  if (g < kL * 1200) stats[g] = 0.f;
  int np1 = (MP_N - kN) * K1P;             // 96*320
  int np2 = (MP_ALL - MP_N - kNLG) * K1P;  // 64*320
  if (g < np1) ab[(size_t)kN * K1P + g] = 0;
  if (g < np2) ab[(size_t)(MP_N + kNLG) * K1P + g] = 0;
}

// ---------------- CSR build ----------------

__global__ void k_zero_int(int* __restrict__ p, int n) {
  int g = blockIdx.x * blockDim.x + threadIdx.x;
  if (g < n) p[g] = 0;
}

__global__ void k_hist(const int* __restrict__ dst, int n, int* __restrict__ deg) {
  int g = blockIdx.x * blockDim.x + threadIdx.x;
  if (g < n) atomicAdd(&deg[dst[g]], 1);
}

__global__ __launch_bounds__(256) void k_scan(int* __restrict__ cursor,
                                              int* __restrict__ offs, int n) {
  __shared__ int part[256];
  int tid = threadIdx.x;
  int chunk = (n + 255) / 256;
  int s0 = tid * chunk;
  int s1 = min(n, s0 + chunk);
  int sum = 0;
  for (int i = s0; i < s1; ++i) sum += cursor[i];
  part[tid] = sum;
  __syncthreads();
  for (int off = 1; off < 256; off <<= 1) {
    int v = (tid >= off) ? part[tid - off] : 0;
    __syncthreads();
    part[tid] += v;
    __syncthreads();
  }
  int run = (tid == 0) ? 0 : part[tid - 1];
  for (int i = s0; i < s1; ++i) {
    int dv = cursor[i];
    offs[i] = run;
    cursor[i] = run;
    run += dv;
  }
  if (tid == 255) offs[n] = run;
}

__global__ void k_fill(const int* __restrict__ dst, int n, int idbase,
                       int* __restrict__ cursor, int* __restrict__ perm) {
  int g = blockIdx.x * blockDim.x + threadIdx.x;
  if (g < n) {
    int pos = atomicAdd(&cursor[dst[g]], 1);
    perm[pos] = idbase + g;
  }
}

// ---------------- merged gather kernels ----------------
// 60000 nodes; node<20000 = main graph, else line graph. One wave per node.
// Writes fp16 row into unified A buffer (main: row=node; lg: row=20096+j).

__global__ void k_gather_all0(
    const unsigned* __restrict__ h16, const unsigned* __restrict__ e16,
    const int* __restrict__ m_src, const int* __restrict__ eattr,
    const int* __restrict__ x, const int* __restrict__ lg_src,
    const int* __restrict__ map2,
    const float* __restrict__ ge1, const float* __restrict__ ge2,
    const float* __restrict__ le1, const float* __restrict__ le2,
    const int* __restrict__ m_offs, const int* __restrict__ m_perm,
    const int* __restrict__ l_offs, const int* __restrict__ l_perm,
    unsigned* __restrict__ outp) {
  int node = blockIdx.x * 4 + (threadIdx.x >> 6);
  int lane = threadIdx.x & 63;
  if (node >= kN + kNLG) return;
  float sx[3], sy[3];
  int orow_idx;
  if (node < kN) {
    const unsigned* hn = h16 + (size_t)node * RU;
#pragma unroll
    for (int q = 0; q < 3; ++q) {
      int u = lane + q * 64;
      if (u < RU) {
        float2 t = upk(hn[u]);
        sx[q] = t.x + ge1[4 * D + 2 * u] + ge2[2 * u];
        sy[q] = t.y + ge1[4 * D + 2 * u + 1] + ge2[2 * u + 1];
      } else { sx[q] = sy[q] = 0.f; }
    }
    int p1 = m_offs[node + 1];
    for (int p = m_offs[node]; p < p1; ++p) {
      int k = m_perm[p];
      const unsigned* hs = h16 + (size_t)m_src[k] * RU;
      const float* e1 = ge1 + (size_t)eattr[2 * k] * D;
      const float* e2 = ge2 + (size_t)eattr[2 * k + 1] * D;
#pragma unroll
      for (int q = 0; q < 3; ++q) {
        int u = lane + q * 64;
        if (u < RU) {
          float2 a = upk(hs[u]);
          sx[q] += a.x + e1[2 * u] + e2[2 * u];
          sy[q] += a.y + e1[2 * u + 1] + e2[2 * u + 1];
        }
      }
    }
    orow_idx = node;
  } else {
    int j = node - kN;
    const unsigned* en = e16 + (size_t)j * RU;
#pragma unroll
    for (int q = 0; q < 3; ++q) {
      int u = lane + q * 64;
      if (u < RU) {
        float2 t = upk(en[u]);
        sx[q] = t.x + le1[119 * D + 2 * u] + le2[2 * u];
        sy[q] = t.y + le1[119 * D + 2 * u + 1] + le2[2 * u + 1];
      } else { sx[q] = sy[q] = 0.f; }
    }
    int p1 = l_offs[j + 1];
    for (int p = l_offs[j]; p < p1; ++p) {
      int k = l_perm[p];
      int a = map2[k];
      const unsigned* es = e16 + (size_t)lg_src[k] * RU;
      const float* e1 = le1 + (size_t)x[2 * a] * D;
      const float* e2 = le2 + (size_t)x[2 * a + 1] * D;
#pragma unroll
      for (int q = 0; q < 3; ++q) {
        int u = lane + q * 64;
        if (u < RU) {
          float2 av = upk(es[u]);
          sx[q] += av.x + e1[2 * u] + e2[2 * u];
          sy[q] += av.y + e1[2 * u + 1] + e2[2 * u + 1];
        }
      }
    }
    orow_idx = MP_N + j;
  }
  unsigned* orow = outp + (size_t)orow_idx * (K1P / 2);
#pragma unroll
  for (int q = 0; q < 3; ++q) {
    int u = lane + q * 64;
    if (u < RU) orow[u] = pk(sx[q], sy[q]);
    else if (u < K1P / 2) orow[u] = 0;
  }
}

__global__ void k_gather_allL(
    const unsigned* __restrict__ h16, const unsigned* __restrict__ e16,
    const int* __restrict__ lg_map, const int* __restrict__ lg_src,
    const int* __restrict__ map2,
    const float* __restrict__ ge1, const float* __restrict__ ge2,
    const float* __restrict__ le1, const float* __restrict__ le2,
    const int* __restrict__ m_offs, const int* __restrict__ m_perm,
    const int* __restrict__ l_offs, const int* __restrict__ l_perm,
    unsigned* __restrict__ outp) {
  int node = blockIdx.x * 4 + (threadIdx.x >> 6);
  int lane = threadIdx.x & 63;
  if (node >= kN + kNLG) return;
  float sx[3], sy[3];
  int orow_idx;
  if (node < kN) {
    const unsigned* hn = h16 + (size_t)node * RU;
#pragma unroll
    for (int q = 0; q < 3; ++q) {
      int u = lane + q * 64;
      if (u < RU) {
        float2 t = upk(hn[u]);
        sx[q] = t.x + ge1[4 * D + 2 * u] + ge2[2 * u];
        sy[q] = t.y + ge1[4 * D + 2 * u + 1] + ge2[2 * u + 1];
      } else { sx[q] = sy[q] = 0.f; }
    }
    int p1 = m_offs[node + 1];
    for (int p = m_offs[node]; p < p1; ++p) {
      int id = m_perm[p];
      int j = (id < kNLG) ? id : id - kNLG;
      const unsigned* hs = h16 + (size_t)lg_map[id] * RU;
      const unsigned* ev = e16 + (size_t)j * RU;
#pragma unroll
      for (int q = 0; q < 3; ++q) {
        int u = lane + q * 64;
        if (u < RU) {
          float2 a = upk(hs[u]), b2 = upk(ev[u]);
          sx[q] += a.x + b2.x;
          sy[q] += a.y + b2.y;
        }
      }
    }
    orow_idx = node;
  } else {
    int j2 = node - kN;
    const unsigned* en = e16 + (size_t)j2 * RU;
#pragma unroll
    for (int q = 0; q < 3; ++q) {
      int u = lane + q * 64;
      if (u < RU) {
        float2 t = upk(en[u]);
        sx[q] = t.x + le1[119 * D + 2 * u] + le2[2 * u];
        sy[q] = t.y + le1[119 * D + 2 * u + 1] + le2[2 * u + 1];
      } else { sx[q] = sy[q] = 0.f; }
    }
    int p1 = l_offs[j2 + 1];
    for (int p = l_offs[j2]; p < p1; ++p) {
      int k = l_perm[p];
      const unsigned* es = e16 + (size_t)lg_src[k] * RU;
      const unsigned* ha = h16 + (size_t)map2[k] * RU;
#pragma unroll
      for (int q = 0; q < 3; ++q) {
        int u = lane + q * 64;
        if (u < RU) {
          float2 a = upk(es[u]), b2 = upk(ha[u]);
          sx[q] += a.x + b2.x;
          sy[q] += a.y + b2.y;
        }
      }
    }
    orow_idx = MP_N + j2;
  }
  unsigned* orow = outp + (size_t)orow_idx * (K1P / 2);
#pragma unroll
  for (int q = 0; q < 3; ++q) {
    int u = lane + q * 64;
    if (u < RU) orow[u] = pk(sx[q], sy[q]);
    else if (u < K1P / 2) orow[u] = 0;
  }
}

// ---------------- misc elementwise ----------------

__global__ void k_embed_pair(const int* __restrict__ idx, const float* __restrict__ t1,
                             const float* __restrict__ t2, float* __restrict__ out,
                             short* __restrict__ hist, int n) {
  int g = blockIdx.x * blockDim.x + threadIdx.x;
  if (g >= n * D) return;
  int i = g / D, d = g - i * D;
  float v = t1[idx[2 * i] * D + d] + t2[idx[2 * i + 1] * D + d];
  out[g] = v;
  hist[g] = f2h(v);
}

__global__ void k_convert_wt(const float* __restrict__ W, short* __restrict__ Wt,
                             int Lc, int K, int Nn, int Kpad, int Npad) {
  int g = blockIdx.x * blockDim.x + threadIdx.x;
  int per = Npad * Kpad;
  if (g >= Lc * per) return;
  int l = g / per, rem = g - l * per;
  int n = rem / Kpad, k = rem - n * Kpad;
  float v = (n < Nn && k < K) ? W[(size_t)l * K * Nn + (size_t)k * Nn + n] : 0.f;
  Wt[g] = f2h(v);
}

// ---------------- dual MFMA GEMM (main tiles + lg tiles, one grid) ----------------

template<bool RELU, bool OUT_F16, bool STATS>
__global__ __launch_bounds__(256) void k_mfma_gemm_dual(
    const short* __restrict__ A,
    const short* __restrict__ BtM, const short* __restrict__ BtL,
    const float* __restrict__ biasM, const float* __restrict__ biasL, int biasN,
    void* __restrict__ Cv, int Ccols, int Cstride, int Kpad,
    int mainLimit, int lgLimit, int lgRowOff,
    float* __restrict__ statsM, float* __restrict__ statsL) {
  __shared__ __align__(16) short ldsA[128 * 32];
  __shared__ __align__(16) short ldsB[128 * 32];
  __shared__ float sd[256];
  const int tid = threadIdx.x;
  const int lane = tid & 63, w = tid >> 6;
  const bool isMain = (int)blockIdx.y < MAIN_TILES;
  const short* Bt = isMain ? BtM : BtL;
  const float* bias = isMain ? biasM : biasL;
  const int rowLimit = isMain ? mainLimit : lgLimit;
  const int rowOff = isMain ? 0 : lgRowOff;
  const int brow = blockIdx.y * 128;
  const int bcol = blockIdx.x * 128;
  const int wr = w >> 1, wc = w & 1;

  if (STATS) sd[tid] = 0.f;

  f32x4 acc[4][4] = {};

  const int sr = tid >> 2;
  const int sc = (tid & 3) * 8;
  char* la = (char*)ldsA + w * 1024;
  char* lb = (char*)ldsB + w * 1024;

  for (int k0 = 0; k0 < Kpad; k0 += 32) {
    __syncthreads();
    const short* gA0 = A + (size_t)(brow + sr) * Kpad + (k0 + sc);
    const short* gB0 = Bt + (size_t)(bcol + sr) * Kpad + (k0 + sc);
    gload_lds16(gA0, la);
    gload_lds16(gA0 + (size_t)64 * Kpad, la + 4096);
    gload_lds16(gB0, lb);
    gload_lds16(gB0 + (size_t)64 * Kpad, lb + 4096);
    __syncthreads();

    const int kq = (lane >> 4) * 16;
    half8 af[4], bf[4];
#pragma unroll
    for (int m = 0; m < 4; ++m) {
      int row = wr * 64 + m * 16 + (lane & 15);
      af[m] = *(const half8*)((const char*)ldsA + row * 64 + kq);
    }
#pragma unroll
    for (int n = 0; n < 4; ++n) {
      int col = wc * 64 + n * 16 + (lane & 15);
      bf[n] = *(const half8*)((const char*)ldsB + col * 64 + kq);
    }
#pragma unroll
    for (int m = 0; m < 4; ++m)
#pragma unroll
      for (int n = 0; n < 4; ++n)
        acc[m][n] = __builtin_amdgcn_mfma_f32_16x16x32_f16(af[m], bf[n], acc[m][n], 0, 0, 0);
  }

  const int r0 = brow + wr * 64;
  const int c0 = bcol + wc * 64;
  float ps[4] = {}, pq[4] = {};
#pragma unroll
  for (int m = 0; m < 4; ++m) {
#pragma unroll
    for (int i = 0; i < 4; ++i) {
      int row = r0 + m * 16 + (lane >> 4) * 4 + i;
      bool rv = row < rowLimit;
#pragma unroll
      for (int n = 0; n < 4; ++n) {
        int col = c0 + n * 16 + (lane & 15);
        float bv = (col < biasN) ? bias[col] : 0.f;
        float v = acc[m][n][i] + bv;
        if (RELU) v = fmaxf(v, 0.f);
        if (rv && col < Ccols) {
          if (OUT_F16)
            ((short*)Cv)[(size_t)row * Cstride + col] = f2h(v);
          else
            ((float*)Cv)[(size_t)(row + rowOff) * Cstride + col] = v;
          if (STATS) { ps[n] += v; pq[n] += v * v; }
        }
      }
    }
  }

  if (STATS) {
#pragma unroll
    for (int n = 0; n < 4; ++n) {
      float s = ps[n], q = pq[n];
      s += __shfl_xor(s, 16); q += __shfl_xor(q, 16);
      s += __shfl_xor(s, 32); q += __shfl_xor(q, 32);
      if ((lane >> 4) == 0) {
        int c = wc * 64 + n * 16 + (lane & 15);
        atomicAdd(&sd[c], s);
        atomicAdd(&sd[128 + c], q);
      }
    }
    __syncthreads();
    float* gs = isMain ? statsM : statsL;
    if (tid < 128) {
      int col = bcol + tid;
      if (col < Ccols) {
        atomicAdd(&gs[col], sd[tid]);
        atomicAdd(&gs[D + col], sd[128 + tid]);
      }
    }
  }
}

// ---------------- merged batchnorm apply ----------------

__global__ void k_bn_apply_all(float* __restrict__ X, short* __restrict__ hist,
                               const float* __restrict__ statsM,
                               const float* __restrict__ statsL,
                               const float* __restrict__ gM, const float* __restrict__ bM,
                               const float* __restrict__ gL, const float* __restrict__ bL,
                               int relu) {
  int g = blockIdx.x * blockDim.x + threadIdx.x;
  if (g >= (kN + kNLG) * D) return;
  int r = g / D;
  int c = g - r * D;
  bool m = r < kN;
  const float* s = m ? statsM : statsL;
  float inv_n = m ? (1.f / kN) : (1.f / kNLG);
  float mu = s[c] * inv_n;
  float var = s[D + c] * inv_n - mu * mu;
  float rs = rsqrtf(var + 1e-5f);
  float gam = (m ? gM : gL)[c];
  float bet = (m ? bM : bL)[c];
  float v = (X[g] - mu) * rs * gam + bet;
  if (relu) v = fmaxf(v, 0.f);
  X[g] = v;
  hist[g] = f2h(v);
}

}  // namespace

extern "C" void kernel_launch(void* const* d_in, const int* in_sizes, int n_in,
                              void* d_out_v, int out_size, void* d_ws, size_t ws_size,
                              hipStream_t stream) {
  const int*   x            = (const int*)d_in[0];
  const int*   edge_index   = (const int*)d_in[1];
  const int*   edge_attr    = (const int*)d_in[2];
  const int*   lg_x         = (const int*)d_in[3];
  const int*   lg_edge_index= (const int*)d_in[4];
  const int*   lg_map       = (const int*)d_in[5];
  const int*   lg_map2      = (const int*)d_in[6];
  const float* node_emb1    = (const float*)d_in[7];
  const float* node_emb2    = (const float*)d_in[8];
  const float* gnn_e_emb1   = (const float*)d_in[9];
  const float* gnn_e_emb2   = (const float*)d_in[10];
  const float* g_emb1       = (const float*)d_in[11];
  const float* g_emb2       = (const float*)d_in[12];
  const float* g_w1         = (const float*)d_in[13];
  const float* g_b1         = (const float*)d_in[14];
  const float* g_w2         = (const float*)d_in[15];
  const float* g_b2         = (const float*)d_in[16];
  const float* g_gamma      = (const float*)d_in[17];
  const float* g_beta       = (const float*)d_in[18];
  const float* lg_emb1      = (const float*)d_in[19];
  const float* lg_emb2      = (const float*)d_in[20];
  const float* lg_w1        = (const float*)d_in[21];
  const float* lg_b1        = (const float*)d_in[22];
  const float* lg_w2        = (const float*)d_in[23];
  const float* lg_b2        = (const float*)d_in[24];
  const float* lg_gamma     = (const float*)d_in[25];
  const float* lg_beta      = (const float*)d_in[26];

  float* out = (float*)d_out_v;
  char*  ws  = (char*)d_ws;

  size_t off = 0;
  auto alloc = [&](size_t bytes) { void* p = ws + off; off = (off + bytes + 255) & ~(size_t)255; return p; };
  short* ab      = (short*)alloc((size_t)MP_ALL * K1P * 2);          // 38.5 MB
  short* hidden  = (short*)alloc((size_t)MP_ALL * N1P * 2);          // 77 MB
  short* hist16  = (short*)alloc((size_t)(kL + 1) * 60000 * D * 2);  // 216 MB
  short* g_w1t   = (short*)alloc((size_t)kL * N1P * K1P * 2);
  short* g_w2t   = (short*)alloc((size_t)kL * N2P * K2P * 2);        // [384 x 640] per layer
  short* lg_w1t  = (short*)alloc((size_t)kL * N1P * K1P * 2);
  short* lg_w2t  = (short*)alloc((size_t)kL * N2P * K2P * 2);
  float* stats   = (float*)alloc(kL * 1200 * 4);
  int* m0_offs = (int*)alloc((kN + 1) * 4);
  int* m0_cur  = (int*)alloc(kN * 4);
  int* m0_perm = (int*)alloc(kE * 4);
  int* mL_offs = (int*)alloc((kN + 1) * 4);
  int* mL_cur  = (int*)alloc(kN * 4);
  int* mL_perm = (int*)alloc(2 * kNLG * 4);
  int* lg_offs = (int*)alloc((kNLG + 1) * 4);
  int* lg_cur  = (int*)alloc(kNLG * 4);
  int* lg_perm = (int*)alloc(kELG * 4);

  auto hptr  = [&](int l) { return out + (size_t)l * 60000 * D; };
  auto h16p  = [&](int l) { return hist16 + (size_t)l * 60000 * D; };
  auto e16p  = [&](int l) { return hist16 + ((size_t)l * 60000 + kN) * D; };

  dim3 b(256);

  // ---- init (stats zero + pad rows), CSR build ----
  k_init<<<(96 * K1P + 255) / 256, b, 0, stream>>>(stats, ab);
  k_zero_int<<<(kN + 255) / 256, b, 0, stream>>>(m0_cur, kN);
  k_zero_int<<<(kN + 255) / 256, b, 0, stream>>>(mL_cur, kN);
  k_zero_int<<<(kNLG + 255) / 256, b, 0, stream>>>(lg_cur, kNLG);
  k_hist<<<(kE + 255) / 256, b, 0, stream>>>(edge_index + kE, kE, m0_cur);
  k_hist<<<(kNLG + 255) / 256, b, 0, stream>>>(lg_map + kNLG, kNLG, mL_cur);
  k_hist<<<(kNLG + 255) / 256, b, 0, stream>>>(lg_map, kNLG, mL_cur);
  k_hist<<<(kELG + 255) / 256, b, 0, stream>>>(lg_edge_index + kELG, kELG, lg_cur);
  k_scan<<<1, b, 0, stream>>>(m0_cur, m0_offs, kN);
  k_scan<<<1, b, 0, stream>>>(mL_cur, mL_offs, kN);
  k_scan<<<1, b, 0, stream>>>(lg_cur, lg_offs, kNLG);
  k_fill<<<(kE + 255) / 256, b, 0, stream>>>(edge_index + kE, kE, 0, m0_cur, m0_perm);
  k_fill<<<(kNLG + 255) / 256, b, 0, stream>>>(lg_map + kNLG, kNLG, 0, mL_cur, mL_perm);
  k_fill<<<(kNLG + 255) / 256, b, 0, stream>>>(lg_map, kNLG, kNLG, mL_cur, mL_perm);
  k_fill<<<(kELG + 255) / 256, b, 0, stream>>>(lg_edge_index + kELG, kELG, 0, lg_cur, lg_perm);

  // ---- weight conversions ----
  {
    int tot1 = kL * N1P * K1P, tot2 = kL * N2P * K2P;
    k_convert_wt<<<(tot1 + 255) / 256, b, 0, stream>>>(g_w1, g_w1t, kL, D, 2 * D, K1P, N1P);
    k_convert_wt<<<(tot2 + 255) / 256, b, 0, stream>>>(g_w2, g_w2t, kL, 2 * D, D, K2P, N2P);
    k_convert_wt<<<(tot1 + 255) / 256, b, 0, stream>>>(lg_w1, lg_w1t, kL, D, 2 * D, K1P, N1P);
    k_convert_wt<<<(tot2 + 255) / 256, b, 0, stream>>>(lg_w2, lg_w2t, kL, 2 * D, D, K2P, N2P);
  }

  k_embed_pair<<<(kN * D + 255) / 256, b, 0, stream>>>(x, node_emb1, node_emb2,
                                                       hptr(0), h16p(0), kN);
  k_embed_pair<<<(kNLG * D + 255) / 256, b, 0, stream>>>(lg_x, gnn_e_emb1, gnn_e_emb2,
                                                         hptr(0) + (size_t)kN * D,
                                                         e16p(0), kNLG);

  for (int l = 0; l < kL; ++l) {
    const float* ge1 = g_emb1 + (size_t)l * 6 * D;
    const float* ge2 = g_emb2 + (size_t)l * 3 * D;
    const float* le1 = lg_emb1 + (size_t)l * 120 * D;
    const float* le2 = lg_emb2 + (size_t)l * 3 * D;
    int relu_tail = (l < kL - 1) ? 1 : 0;
    float* slot = stats + (size_t)l * 1200;          // [main sum,sq | lg sum,sq]

    // merged gather -> unified A
    if (l == 0)
      k_gather_all0<<<(kN + kNLG + 3) / 4, b, 0, stream>>>(
          (const unsigned*)h16p(0), (const unsigned*)e16p(0),
          edge_index, edge_attr, x, lg_edge_index, lg_map2,
          ge1, ge2, le1, le2, m0_offs, m0_perm, lg_offs, lg_perm, (unsigned*)ab);
    else
      k_gather_allL<<<(kN + kNLG + 3) / 4, b, 0, stream>>>(
          (const unsigned*)h16p(l), (const unsigned*)e16p(l),
          lg_map, lg_edge_index, lg_map2,
          ge1, ge2, le1, le2, mL_offs, mL_perm, lg_offs, lg_perm, (unsigned*)ab);

    // dual GEMM1: hidden = relu(A @ W1 + b1)
    k_mfma_gemm_dual<true, true, false><<<dim3(N1P / 128, MP_ALL / 128), b, 0, stream>>>(
        ab, g_w1t + (size_t)l * N1P * K1P, lg_w1t + (size_t)l * N1P * K1P,
        g_b1 + (size_t)l * 2 * D, lg_b1 + (size_t)l * 2 * D, 2 * D,
        hidden, N1P, N1P, K1P, MP_ALL, MP_ALL, 0, nullptr, nullptr);

    // dual GEMM2 + fused BN stats: out rows [60000][300]
    k_mfma_gemm_dual<false, false, true><<<dim3(N2P / 128, MP_ALL / 128), b, 0, stream>>>(
        hidden, g_w2t + (size_t)l * N2P * K2P, lg_w2t + (size_t)l * N2P * K2P,
        g_b2 + (size_t)l * D, lg_b2 + (size_t)l * D, D,
        hptr(l + 1), D, D, K2P, kN, MP_N + kNLG, -(MP_N - kN),
        slot, slot + 600);

    // merged BN apply (+ fp16 history write)
    k_bn_apply_all<<<((kN + kNLG) * D + 255) / 256, b, 0, stream>>>(
        hptr(l + 1), h16p(l + 1), slot, slot + 600,
        g_gamma + (size_t)l * D, g_beta + (size_t)l * D,
        lg_gamma + (size_t)l * D, lg_beta + (size_t)l * D, relu_tail);
  }
}

// Round 8
// 1712.892 us; speedup vs baseline: 4.1239x; 1.0693x over previous
//
#include <hip/hip_runtime.h>

#define D 300

namespace {

constexpr int kN   = 20000;
constexpr int kNLG = 40000;
constexpr int kE   = 80000;
constexpr int kELG = 200000;
constexpr int kL   = 5;

constexpr int K1P = 320;        // padded feature dim (fp16) = A-row width
constexpr int N1P = 640;
constexpr int K2P = 640;
constexpr int N2P = 384;
constexpr int MP_N   = 20096;   // main rows padded (157 tiles)
constexpr int MP_ALL = 60160;   // + 40064 lg rows = 470 tiles
constexpr int MAIN_TILES = 157;
constexpr int RH = 320;         // halves per padded history row
constexpr int RQ = 40;          // uint4 per padded row

typedef __attribute__((ext_vector_type(8))) _Float16 half8;
typedef __attribute__((ext_vector_type(2))) _Float16 half2v;
typedef __attribute__((ext_vector_type(4))) float f32x4;

__device__ inline short f2h(float f) {
  _Float16 h = (_Float16)f;
  return __builtin_bit_cast(short, h);
}

__device__ inline float2 upk(unsigned u) {
  half2v h = __builtin_bit_cast(half2v, u);
  return make_float2((float)h.x, (float)h.y);
}

__device__ inline unsigned pk(float a, float b) {
  half2v h;
  h.x = (_Float16)a;
  h.y = (_Float16)b;
  return __builtin_bit_cast(unsigned, h);
}

__device__ inline void addrow(float* acc, uint4 r) {
  float2 t0 = upk(r.x), t1 = upk(r.y), t2 = upk(r.z), t3 = upk(r.w);
  acc[0] += t0.x; acc[1] += t0.y; acc[2] += t1.x; acc[3] += t1.y;
  acc[4] += t2.x; acc[5] += t2.y; acc[6] += t3.x; acc[7] += t3.y;
}

__device__ inline uint4 pk4(const float* a) {
  uint4 r;
  r.x = pk(a[0], a[1]); r.y = pk(a[2], a[3]);
  r.z = pk(a[4], a[5]); r.w = pk(a[6], a[7]);
  return r;
}

__device__ inline void gload_lds16(const void* g, void* l) {
  __builtin_amdgcn_global_load_lds(
      (const __attribute__((address_space(1))) void*)g,
      (__attribute__((address_space(3))) void*)l, 16, 0, 0);
}

// ---------------- init: zero stats + A-buffer pad rows ----------------

__global__ void k_init(float* __restrict__ stats, short* __restrict__ ab) {
  int g = blockIdx.x * blockDim.x + threadIdx.x;
  if (g < kL * 1200) stats[g] = 0.f;
  int np1 = (MP_N - kN) * K1P;             // 96*320
  int np2 = (MP_ALL - MP_N - kNLG) * K1P;  // 64*320
  if (g < np1) ab[(size_t)kN * K1P + g] = 0;
  if (g < np2) ab[(size_t)(MP_N + kNLG) * K1P + g] = 0;
}

// ---------------- CSR build ----------------

__global__ void k_zero_int(int* __restrict__ p, int n) {
  int g = blockIdx.x * blockDim.x + threadIdx.x;
  if (g < n) p[g] = 0;
}

__global__ void k_hist(const int* __restrict__ dst, int n, int* __restrict__ deg) {
  int g = blockIdx.x * blockDim.x + threadIdx.x;
  if (g < n) atomicAdd(&deg[dst[g]], 1);
}

__global__ __launch_bounds__(256) void k_scan(int* __restrict__ cursor,
                                              int* __restrict__ offs, int n) {
  __shared__ int part[256];
  int tid = threadIdx.x;
  int chunk = (n + 255) / 256;
  int s0 = tid * chunk;
  int s1 = min(n, s0 + chunk);
  int sum = 0;
  for (int i = s0; i < s1; ++i) sum += cursor[i];
  part[tid] = sum;
  __syncthreads();
  for (int off = 1; off < 256; off <<= 1) {
    int v = (tid >= off) ? part[tid - off] : 0;
    __syncthreads();
    part[tid] += v;
    __syncthreads();
  }
  int run = (tid == 0) ? 0 : part[tid - 1];
  for (int i = s0; i < s1; ++i) {
    int dv = cursor[i];
    offs[i] = run;
    cursor[i] = run;
    run += dv;
  }
  if (tid == 255) offs[n] = run;
}

__global__ void k_fill(const int* __restrict__ dst, int n, int idbase,
                       int* __restrict__ cursor, int* __restrict__ perm) {
  int g = blockIdx.x * blockDim.x + threadIdx.x;
  if (g < n) {
    int pos = atomicAdd(&cursor[dst[g]], 1);
    perm[pos] = idbase + g;
  }
}

// ---------------- precompute: self vectors + padded layer-0 tables ----------------

// slv layout: [kL][2][320] fp32 (graph 0 = main emb1[4]+emb2[0], 1 = lg emb1[119]+emb2[0])
__global__ void k_selfvec(const float* __restrict__ g1, const float* __restrict__ g2,
                          const float* __restrict__ l1, const float* __restrict__ l2,
                          float* __restrict__ slv) {
  int g = blockIdx.x * blockDim.x + threadIdx.x;
  if (g >= kL * 640) return;
  int l = g / 640, rem = g - l * 640;
  int gr = rem / 320, c = rem - gr * 320;
  float v = 0.f;
  if (c < D) {
    if (gr == 0) v = g1[(size_t)l * 6 * D + 4 * D + c] + g2[(size_t)l * 3 * D + c];
    else         v = l1[(size_t)l * 120 * D + 119 * D + c] + l2[(size_t)l * 3 * D + c];
  }
  slv[g] = v;
}

// fp32 [rows][300] -> fp16 [rows][320]
__global__ void k_pad_tab(const float* __restrict__ T, short* __restrict__ O, int rows) {
  int g = blockIdx.x * blockDim.x + threadIdx.x;
  if (g >= rows * RH) return;
  int r = g / RH, c = g - r * RH;
  O[g] = (c < D) ? f2h(T[(size_t)r * D + c]) : (short)0;
}

// ---------------- gather kernels (padded rows, staged indices, unrolled) ----------------
// one wave per node; lanes 0..39 each own 16B of the 640B row.

__global__ void k_gather_all0(
    const uint4* __restrict__ h16, const uint4* __restrict__ e16,
    const int* __restrict__ m_src, const int* __restrict__ eattr,
    const int* __restrict__ x, const int* __restrict__ lg_src,
    const int* __restrict__ map2,
    const uint4* __restrict__ t1m, const uint4* __restrict__ t2m,
    const uint4* __restrict__ t1l, const uint4* __restrict__ t2l,
    const float* __restrict__ slvM, const float* __restrict__ slvL,
    const int* __restrict__ m_offs, const int* __restrict__ m_perm,
    const int* __restrict__ l_offs, const int* __restrict__ l_perm,
    uint4* __restrict__ ab) {
  int node = blockIdx.x * 4 + (threadIdx.x >> 6);
  int lane = threadIdx.x & 63;
  if (node >= kN + kNLG) return;
  bool act = lane < RQ;
  int ll = act ? lane : 0;
  bool isM = node < kN;
  int j = isM ? node : node - kN;
  const uint4* selfrow = isM ? (h16 + (size_t)node * RQ) : (e16 + (size_t)j * RQ);
  const float* sv = (isM ? slvM : slvL) + ll * 8;
  const int* offs = isM ? m_offs : l_offs;
  const int* permp = isM ? m_perm : l_perm;
  const uint4* bA = isM ? h16 : e16;
  const uint4* bT1 = isM ? t1m : t1l;
  const uint4* bT2 = isM ? t2m : t2l;

  float acc[8];
  {
    uint4 s = selfrow[ll];
    float2 t0 = upk(s.x), t1 = upk(s.y), t2 = upk(s.z), t3 = upk(s.w);
    acc[0] = t0.x + sv[0]; acc[1] = t0.y + sv[1];
    acc[2] = t1.x + sv[2]; acc[3] = t1.y + sv[3];
    acc[4] = t2.x + sv[4]; acc[5] = t2.y + sv[5];
    acc[6] = t3.x + sv[6]; acc[7] = t3.y + sv[7];
  }

  int p0 = offs[j], p1 = offs[j + 1];
  for (int pb = p0; pb < p1; pb += 64) {
    int cnt = min(64, p1 - pb);
    int e_ = permp[pb + ((lane < cnt) ? lane : 0)];
    int r1, r2, r3;
    if (isM) {
      r1 = m_src[e_];
      r2 = eattr[2 * e_];
      r3 = eattr[2 * e_ + 1];
    } else {
      r1 = lg_src[e_];
      int a = map2[e_];
      r2 = x[2 * a];
      r3 = x[2 * a + 1];
    }
    int t = 0;
    for (; t + 1 < cnt; t += 2) {
      int a0 = __shfl(r1, t), b0 = __shfl(r2, t), c0 = __shfl(r3, t);
      int a1 = __shfl(r1, t + 1), b1 = __shfl(r2, t + 1), c1 = __shfl(r3, t + 1);
      uint4 x0 = bA[(size_t)a0 * RQ + ll];
      uint4 y0 = bT1[(size_t)b0 * RQ + ll];
      uint4 z0 = bT2[(size_t)c0 * RQ + ll];
      uint4 x1 = bA[(size_t)a1 * RQ + ll];
      uint4 y1 = bT1[(size_t)b1 * RQ + ll];
      uint4 z1 = bT2[(size_t)c1 * RQ + ll];
      addrow(acc, x0); addrow(acc, y0); addrow(acc, z0);
      addrow(acc, x1); addrow(acc, y1); addrow(acc, z1);
    }
    if (t < cnt) {
      int a0 = __shfl(r1, t), b0 = __shfl(r2, t), c0 = __shfl(r3, t);
      uint4 x0 = bA[(size_t)a0 * RQ + ll];
      uint4 y0 = bT1[(size_t)b0 * RQ + ll];
      uint4 z0 = bT2[(size_t)c0 * RQ + ll];
      addrow(acc, x0); addrow(acc, y0); addrow(acc, z0);
    }
  }
  if (act) ab[(size_t)(isM ? node : MP_N + j) * RQ + ll] = pk4(acc);
}

__global__ void k_gather_allL(
    const uint4* __restrict__ h16, const uint4* __restrict__ e16,
    const int* __restrict__ lg_map, const int* __restrict__ lg_src,
    const int* __restrict__ map2,
    const float* __restrict__ slvM, const float* __restrict__ slvL,
    const int* __restrict__ m_offs, const int* __restrict__ m_perm,
    const int* __restrict__ l_offs, const int* __restrict__ l_perm,
    uint4* __restrict__ ab) {
  int node = blockIdx.x * 4 + (threadIdx.x >> 6);
  int lane = threadIdx.x & 63;
  if (node >= kN + kNLG) return;
  bool act = lane < RQ;
  int ll = act ? lane : 0;
  bool isM = node < kN;
  int j = isM ? node : node - kN;
  const uint4* selfrow = isM ? (h16 + (size_t)node * RQ) : (e16 + (size_t)j * RQ);
  const float* sv = (isM ? slvM : slvL) + ll * 8;
  const int* offs = isM ? m_offs : l_offs;
  const int* permp = isM ? m_perm : l_perm;
  const uint4* bA = isM ? h16 : e16;
  const uint4* bB = isM ? e16 : h16;

  float acc[8];
  {
    uint4 s = selfrow[ll];
    float2 t0 = upk(s.x), t1 = upk(s.y), t2 = upk(s.z), t3 = upk(s.w);
    acc[0] = t0.x + sv[0]; acc[1] = t0.y + sv[1];
    acc[2] = t1.x + sv[2]; acc[3] = t1.y + sv[3];
    acc[4] = t2.x + sv[4]; acc[5] = t2.y + sv[5];
    acc[6] = t3.x + sv[6]; acc[7] = t3.y + sv[7];
  }

  int p0 = offs[j], p1 = offs[j + 1];
  for (int pb = p0; pb < p1; pb += 64) {
    int cnt = min(64, p1 - pb);
    int e_ = permp[pb + ((lane < cnt) ? lane : 0)];
    int ra, rb;
    if (isM) {
      ra = lg_map[e_];                          // h-row
      rb = (e_ < kNLG) ? e_ : e_ - kNLG;        // e-row
    } else {
      ra = lg_src[e_];                          // e-row
      rb = map2[e_];                            // h-row
    }
    int t = 0;
    for (; t + 1 < cnt; t += 2) {
      int a0 = __shfl(ra, t), b0 = __shfl(rb, t);
      int a1 = __shfl(ra, t + 1), b1 = __shfl(rb, t + 1);
      uint4 x0 = bA[(size_t)a0 * RQ + ll];
      uint4 y0 = bB[(size_t)b0 * RQ + ll];
      uint4 x1 = bA[(size_t)a1 * RQ + ll];
      uint4 y1 = bB[(size_t)b1 * RQ + ll];
      addrow(acc, x0); addrow(acc, y0);
      addrow(acc, x1); addrow(acc, y1);
    }
    if (t < cnt) {
      int a0 = __shfl(ra, t), b0 = __shfl(rb, t);
      uint4 x0 = bA[(size_t)a0 * RQ + ll];
      uint4 y0 = bB[(size_t)b0 * RQ + ll];
      addrow(acc, x0); addrow(acc, y0);
    }
  }
  if (act) ab[(size_t)(isM ? node : MP_N + j) * RQ + ll] = pk4(acc);
}

// ---------------- misc elementwise ----------------

__global__ void k_embed_pair(const int* __restrict__ idx, const float* __restrict__ t1,
                             const float* __restrict__ t2, float* __restrict__ out,
                             short* __restrict__ hist, int n) {
  int g = blockIdx.x * blockDim.x + threadIdx.x;
  if (g >= n * RH) return;
  int i = g / RH, c = g - i * RH;
  short hv = 0;
  if (c < D) {
    float v = t1[(size_t)idx[2 * i] * D + c] + t2[(size_t)idx[2 * i + 1] * D + c];
    out[(size_t)i * D + c] = v;
    hv = f2h(v);
  }
  hist[g] = hv;
}

__global__ void k_convert_wt(const float* __restrict__ W, short* __restrict__ Wt,
                             int Lc, int K, int Nn, int Kpad, int Npad) {
  int g = blockIdx.x * blockDim.x + threadIdx.x;
  int per = Npad * Kpad;
  if (g >= Lc * per) return;
  int l = g / per, rem = g - l * per;
  int n = rem / Kpad, k = rem - n * Kpad;
  float v = (n < Nn && k < K) ? W[(size_t)l * K * Nn + (size_t)k * Nn + n] : 0.f;
  Wt[g] = f2h(v);
}

// ---------------- dual MFMA GEMM ----------------

template<bool RELU, bool OUT_F16, bool STATS>
__global__ __launch_bounds__(256) void k_mfma_gemm_dual(
    const short* __restrict__ A,
    const short* __restrict__ BtM, const short* __restrict__ BtL,
    const float* __restrict__ biasM, const float* __restrict__ biasL, int biasN,
    void* __restrict__ Cv, int Ccols, int Cstride, int Kpad,
    int mainLimit, int lgLimit, int lgRowOff,
    float* __restrict__ statsM, float* __restrict__ statsL) {
  __shared__ __align__(16) short ldsA[128 * 32];
  __shared__ __align__(16) short ldsB[128 * 32];
  __shared__ float sd[256];
  const int tid = threadIdx.x;
  const int lane = tid & 63, w = tid >> 6;
  const bool isMain = (int)blockIdx.y < MAIN_TILES;
  const short* Bt = isMain ? BtM : BtL;
  const float* bias = isMain ? biasM : biasL;
  const int rowLimit = isMain ? mainLimit : lgLimit;
  const int rowOff = isMain ? 0 : lgRowOff;
  const int brow = blockIdx.y * 128;
  const int bcol = blockIdx.x * 128;
  const int wr = w >> 1, wc = w & 1;

  if (STATS) sd[tid] = 0.f;

  f32x4 acc[4][4] = {};

  const int sr = tid >> 2;
  const int sc = (tid & 3) * 8;
  char* la = (char*)ldsA + w * 1024;
  char* lb = (char*)ldsB + w * 1024;

  for (int k0 = 0; k0 < Kpad; k0 += 32) {
    __syncthreads();
    const short* gA0 = A + (size_t)(brow + sr) * Kpad + (k0 + sc);
    const short* gB0 = Bt + (size_t)(bcol + sr) * Kpad + (k0 + sc);
    gload_lds16(gA0, la);
    gload_lds16(gA0 + (size_t)64 * Kpad, la + 4096);
    gload_lds16(gB0, lb);
    gload_lds16(gB0 + (size_t)64 * Kpad, lb + 4096);
    __syncthreads();

    const int kq = (lane >> 4) * 16;
    half8 af[4], bf[4];
#pragma unroll
    for (int m = 0; m < 4; ++m) {
      int row = wr * 64 + m * 16 + (lane & 15);
      af[m] = *(const half8*)((const char*)ldsA + row * 64 + kq);
    }
#pragma unroll
    for (int n = 0; n < 4; ++n) {
      int col = wc * 64 + n * 16 + (lane & 15);
      bf[n] = *(const half8*)((const char*)ldsB + col * 64 + kq);
    }
#pragma unroll
    for (int m = 0; m < 4; ++m)
#pragma unroll
      for (int n = 0; n < 4; ++n)
        acc[m][n] = __builtin_amdgcn_mfma_f32_16x16x32_f16(af[m], bf[n], acc[m][n], 0, 0, 0);
  }

  const int r0 = brow + wr * 64;
  const int c0 = bcol + wc * 64;
  float ps[4] = {}, pq[4] = {};
#pragma unroll
  for (int m = 0; m < 4; ++m) {
#pragma unroll
    for (int i = 0; i < 4; ++i) {
      int row = r0 + m * 16 + (lane >> 4) * 4 + i;
      bool rv = row < rowLimit;
#pragma unroll
      for (int n = 0; n < 4; ++n) {
        int col = c0 + n * 16 + (lane & 15);
        float bv = (col < biasN) ? bias[col] : 0.f;
        float v = acc[m][n][i] + bv;
        if (RELU) v = fmaxf(v, 0.f);
        if (rv && col < Ccols) {
          if (OUT_F16)
            ((short*)Cv)[(size_t)row * Cstride + col] = f2h(v);
          else
            ((float*)Cv)[(size_t)(row + rowOff) * Cstride + col] = v;
          if (STATS) { ps[n] += v; pq[n] += v * v; }
        }
      }
    }
  }

  if (STATS) {
#pragma unroll
    for (int n = 0; n < 4; ++n) {
      float s = ps[n], q = pq[n];
      s += __shfl_xor(s, 16); q += __shfl_xor(q, 16);
      s += __shfl_xor(s, 32); q += __shfl_xor(q, 32);
      if ((lane >> 4) == 0) {
        int c = wc * 64 + n * 16 + (lane & 15);
        atomicAdd(&sd[c], s);
        atomicAdd(&sd[128 + c], q);
      }
    }
    __syncthreads();
    float* gs = isMain ? statsM : statsL;
    if (tid < 128) {
      int col = bcol + tid;
      if (col < Ccols) {
        atomicAdd(&gs[col], sd[tid]);
        atomicAdd(&gs[D + col], sd[128 + tid]);
      }
    }
  }
}

// ---------------- merged batchnorm apply (writes padded fp16 history) ----------------

__global__ void k_bn_apply_all(float* __restrict__ X, short* __restrict__ hist,
                               const float* __restrict__ statsM,
                               const float* __restrict__ statsL,
                               const float* __restrict__ gM, const float* __restrict__ bM,
                               const float* __restrict__ gL, const float* __restrict__ bL,
                               int relu) {
  int g = blockIdx.x * blockDim.x + threadIdx.x;
  if (g >= (kN + kNLG) * RH) return;
  int r = g / RH;
  int c = g - r * RH;
  short hv = 0;
  if (c < D) {
    bool m = r < kN;
    const float* s = m ? statsM : statsL;
    float inv_n = m ? (1.f / kN) : (1.f / kNLG);
    float mu = s[c] * inv_n;
    float var = s[D + c] * inv_n - mu * mu;
    float rs = rsqrtf(var + 1e-5f);
    float gam = (m ? gM : gL)[c];
    float bet = (m ? bM : bL)[c];
    float v = (X[(size_t)r * D + c] - mu) * rs * gam + bet;
    if (relu) v = fmaxf(v, 0.f);
    X[(size_t)r * D + c] = v;
    hv = f2h(v);
  }
  hist[g] = hv;
}

}  // namespace

extern "C" void kernel_launch(void* const* d_in, const int* in_sizes, int n_in,
                              void* d_out_v, int out_size, void* d_ws, size_t ws_size,
                              hipStream_t stream) {
  const int*   x            = (const int*)d_in[0];
  const int*   edge_index   = (const int*)d_in[1];
  const int*   edge_attr    = (const int*)d_in[2];
  const int*   lg_x         = (const int*)d_in[3];
  const int*   lg_edge_index= (const int*)d_in[4];
  const int*   lg_map       = (const int*)d_in[5];
  const int*   lg_map2      = (const int*)d_in[6];
  const float* node_emb1    = (const float*)d_in[7];
  const float* node_emb2    = (const float*)d_in[8];
  const float* gnn_e_emb1   = (const float*)d_in[9];
  const float* gnn_e_emb2   = (const float*)d_in[10];
  const float* g_emb1       = (const float*)d_in[11];
  const float* g_emb2       = (const float*)d_in[12];
  const float* g_w1         = (const float*)d_in[13];
  const float* g_b1         = (const float*)d_in[14];
  const float* g_w2         = (const float*)d_in[15];
  const float* g_b2         = (const float*)d_in[16];
  const float* g_gamma      = (const float*)d_in[17];
  const float* g_beta       = (const float*)d_in[18];
  const float* lg_emb1      = (const float*)d_in[19];
  const float* lg_emb2      = (const float*)d_in[20];
  const float* lg_w1        = (const float*)d_in[21];
  const float* lg_b1        = (const float*)d_in[22];
  const float* lg_w2        = (const float*)d_in[23];
  const float* lg_b2        = (const float*)d_in[24];
  const float* lg_gamma     = (const float*)d_in[25];
  const float* lg_beta      = (const float*)d_in[26];

  float* out = (float*)d_out_v;
  char*  ws  = (char*)d_ws;

  size_t off = 0;
  auto alloc = [&](size_t bytes) { void* p = ws + off; off = (off + bytes + 255) & ~(size_t)255; return p; };
  short* ab      = (short*)alloc((size_t)MP_ALL * K1P * 2);          // 38.5 MB
  short* hidden  = (short*)alloc((size_t)MP_ALL * N1P * 2);          // 77 MB
  short* hist16  = (short*)alloc((size_t)(kL + 1) * 60000 * RH * 2); // 230 MB
  short* g_w1t   = (short*)alloc((size_t)kL * N1P * K1P * 2);
  short* g_w2t   = (short*)alloc((size_t)kL * N2P * K2P * 2);
  short* lg_w1t  = (short*)alloc((size_t)kL * N1P * K1P * 2);
  short* lg_w2t  = (short*)alloc((size_t)kL * N2P * K2P * 2);
  float* stats   = (float*)alloc(kL * 1200 * 4);
  float* slv     = (float*)alloc(kL * 640 * 4);
  short* t1m     = (short*)alloc(6 * RH * 2);
  short* t2m     = (short*)alloc(3 * RH * 2);
  short* t1l     = (short*)alloc(120 * RH * 2);
  short* t2l     = (short*)alloc(3 * RH * 2);
  int* m0_offs = (int*)alloc((kN + 1) * 4);
  int* m0_cur  = (int*)alloc(kN * 4);
  int* m0_perm = (int*)alloc(kE * 4);
  int* mL_offs = (int*)alloc((kN + 1) * 4);
  int* mL_cur  = (int*)alloc(kN * 4);
  int* mL_perm = (int*)alloc(2 * kNLG * 4);
  int* lg_offs = (int*)alloc((kNLG + 1) * 4);
  int* lg_cur  = (int*)alloc(kNLG * 4);
  int* lg_perm = (int*)alloc(kELG * 4);

  auto hptr  = [&](int l) { return out + (size_t)l * 60000 * D; };
  auto h16p  = [&](int l) { return hist16 + (size_t)l * 60000 * RH; };
  auto e16p  = [&](int l) { return hist16 + ((size_t)l * 60000 + kN) * RH; };

  dim3 b(256);

  // ---- init, CSR build, precompute ----
  k_init<<<(96 * K1P + 255) / 256, b, 0, stream>>>(stats, ab);
  k_zero_int<<<(kN + 255) / 256, b, 0, stream>>>(m0_cur, kN);
  k_zero_int<<<(kN + 255) / 256, b, 0, stream>>>(mL_cur, kN);
  k_zero_int<<<(kNLG + 255) / 256, b, 0, stream>>>(lg_cur, kNLG);
  k_hist<<<(kE + 255) / 256, b, 0, stream>>>(edge_index + kE, kE, m0_cur);
  k_hist<<<(kNLG + 255) / 256, b, 0, stream>>>(lg_map + kNLG, kNLG, mL_cur);
  k_hist<<<(kNLG + 255) / 256, b, 0, stream>>>(lg_map, kNLG, mL_cur);
  k_hist<<<(kELG + 255) / 256, b, 0, stream>>>(lg_edge_index + kELG, kELG, lg_cur);
  k_scan<<<1, b, 0, stream>>>(m0_cur, m0_offs, kN);
  k_scan<<<1, b, 0, stream>>>(mL_cur, mL_offs, kN);
  k_scan<<<1, b, 0, stream>>>(lg_cur, lg_offs, kNLG);
  k_fill<<<(kE + 255) / 256, b, 0, stream>>>(edge_index + kE, kE, 0, m0_cur, m0_perm);
  k_fill<<<(kNLG + 255) / 256, b, 0, stream>>>(lg_map + kNLG, kNLG, 0, mL_cur, mL_perm);
  k_fill<<<(kNLG + 255) / 256, b, 0, stream>>>(lg_map, kNLG, kNLG, mL_cur, mL_perm);
  k_fill<<<(kELG + 255) / 256, b, 0, stream>>>(lg_edge_index + kELG, kELG, 0, lg_cur, lg_perm);
  k_selfvec<<<(kL * 640 + 255) / 256, b, 0, stream>>>(g_emb1, g_emb2, lg_emb1, lg_emb2, slv);
  k_pad_tab<<<(6 * RH + 255) / 256, b, 0, stream>>>(g_emb1, t1m, 6);
  k_pad_tab<<<(3 * RH + 255) / 256, b, 0, stream>>>(g_emb2, t2m, 3);
  k_pad_tab<<<(120 * RH + 255) / 256, b, 0, stream>>>(lg_emb1, t1l, 120);
  k_pad_tab<<<(3 * RH + 255) / 256, b, 0, stream>>>(lg_emb2, t2l, 3);

  // ---- weight conversions ----
  {
    int tot1 = kL * N1P * K1P, tot2 = kL * N2P * K2P;
    k_convert_wt<<<(tot1 + 255) / 256, b, 0, stream>>>(g_w1, g_w1t, kL, D, 2 * D, K1P, N1P);
    k_convert_wt<<<(tot2 + 255) / 256, b, 0, stream>>>(g_w2, g_w2t, kL, 2 * D, D, K2P, N2P);
    k_convert_wt<<<(tot1 + 255) / 256, b, 0, stream>>>(lg_w1, lg_w1t, kL, D, 2 * D, K1P, N1P);
    k_convert_wt<<<(tot2 + 255) / 256, b, 0, stream>>>(lg_w2, lg_w2t, kL, 2 * D, D, K2P, N2P);
  }

  k_embed_pair<<<(kN * RH + 255) / 256, b, 0, stream>>>(x, node_emb1, node_emb2,
                                                        hptr(0), h16p(0), kN);
  k_embed_pair<<<(kNLG * RH + 255) / 256, b, 0, stream>>>(lg_x, gnn_e_emb1, gnn_e_emb2,
                                                          hptr(0) + (size_t)kN * D,
                                                          e16p(0), kNLG);

  for (int l = 0; l < kL; ++l) {
    int relu_tail = (l < kL - 1) ? 1 : 0;
    float* slot = stats + (size_t)l * 1200;
    const float* slvM = slv + (size_t)l * 640;
    const float* slvL = slvM + 320;

    if (l == 0)
      k_gather_all0<<<(kN + kNLG + 3) / 4, b, 0, stream>>>(
          (const uint4*)h16p(0), (const uint4*)e16p(0),
          edge_index, edge_attr, x, lg_edge_index, lg_map2,
          (const uint4*)t1m, (const uint4*)t2m, (const uint4*)t1l, (const uint4*)t2l,
          slvM, slvL, m0_offs, m0_perm, lg_offs, lg_perm, (uint4*)ab);
    else
      k_gather_allL<<<(kN + kNLG + 3) / 4, b, 0, stream>>>(
          (const uint4*)h16p(l), (const uint4*)e16p(l),
          lg_map, lg_edge_index, lg_map2,
          slvM, slvL, mL_offs, mL_perm, lg_offs, lg_perm, (uint4*)ab);

    k_mfma_gemm_dual<true, true, false><<<dim3(N1P / 128, MP_ALL / 128), b, 0, stream>>>(
        ab, g_w1t + (size_t)l * N1P * K1P, lg_w1t + (size_t)l * N1P * K1P,
        g_b1 + (size_t)l * 2 * D, lg_b1 + (size_t)l * 2 * D, 2 * D,
        hidden, N1P, N1P, K1P, MP_ALL, MP_ALL, 0, nullptr, nullptr);

    k_mfma_gemm_dual<false, false, true><<<dim3(N2P / 128, MP_ALL / 128), b, 0, stream>>>(
        hidden, g_w2t + (size_t)l * N2P * K2P, lg_w2t + (size_t)l * N2P * K2P,
        g_b2 + (size_t)l * D, lg_b2 + (size_t)l * D, D,
        hptr(l + 1), D, D, K2P, kN, MP_N + kNLG, -(MP_N - kN),
        slot, slot + 600);

    k_bn_apply_all<<<((kN + kNLG) * RH + 255) / 256, b, 0, stream>>>(
        hptr(l + 1), h16p(l + 1), slot, slot + 600,
        g_gamma + (size_t)l * D, g_beta + (size_t)l * D,
        lg_gamma + (size_t)l * D, lg_beta + (size_t)l * D, relu_tail);
  }
}

// Round 9
// 1538.577 us; speedup vs baseline: 4.5911x; 1.1133x over previous
//
#include <hip/hip_runtime.h>

#define D 300

namespace {

constexpr int kN   = 20000;
constexpr int kNLG = 40000;
constexpr int kE   = 80000;
constexpr int kELG = 200000;
constexpr int kL   = 5;

constexpr int K1P = 320;        // padded feature dim (fp16) = A-row width
constexpr int N1P = 640;
constexpr int K2P = 640;
constexpr int N2P = 384;
constexpr int MP_N   = 20096;   // main rows padded (157 tiles)
constexpr int MP_ALL = 60160;   // + 40064 lg rows = 470 tiles
constexpr int MAIN_TILES = 157;
constexpr int RH = 320;         // halves per padded history row
constexpr int RQ = 40;          // uint4 per padded row

typedef __attribute__((ext_vector_type(8))) _Float16 half8;
typedef __attribute__((ext_vector_type(2))) _Float16 half2v;
typedef __attribute__((ext_vector_type(4))) float f32x4;

__device__ inline short f2h(float f) {
  _Float16 h = (_Float16)f;
  return __builtin_bit_cast(short, h);
}

__device__ inline float h2f(short s) {
  return (float)__builtin_bit_cast(_Float16, s);
}

__device__ inline float2 upk(unsigned u) {
  half2v h = __builtin_bit_cast(half2v, u);
  return make_float2((float)h.x, (float)h.y);
}

__device__ inline unsigned pk(float a, float b) {
  half2v h;
  h.x = (_Float16)a;
  h.y = (_Float16)b;
  return __builtin_bit_cast(unsigned, h);
}

__device__ inline void addrow(float* acc, uint4 r) {
  float2 t0 = upk(r.x), t1 = upk(r.y), t2 = upk(r.z), t3 = upk(r.w);
  acc[0] += t0.x; acc[1] += t0.y; acc[2] += t1.x; acc[3] += t1.y;
  acc[4] += t2.x; acc[5] += t2.y; acc[6] += t3.x; acc[7] += t3.y;
}

__device__ inline uint4 pk4(const float* a) {
  uint4 r;
  r.x = pk(a[0], a[1]); r.y = pk(a[2], a[3]);
  r.z = pk(a[4], a[5]); r.w = pk(a[6], a[7]);
  return r;
}

__device__ inline void gload_lds16(const void* g, void* l) {
  __builtin_amdgcn_global_load_lds(
      (const __attribute__((address_space(1))) void*)g,
      (__attribute__((address_space(3))) void*)l, 16, 0, 0);
}

// ---------------- init: stats, ab pad rows, CSR cursors ----------------

__global__ void k_init(float* __restrict__ stats, short* __restrict__ ab,
                       int* __restrict__ m0_cur, int* __restrict__ mL_cur,
                       int* __restrict__ lg_cur) {
  int g = blockIdx.x * blockDim.x + threadIdx.x;
  if (g < kL * 1200) stats[g] = 0.f;
  int np1 = (MP_N - kN) * K1P;
  int np2 = (MP_ALL - MP_N - kNLG) * K1P;
  if (g < np1) ab[(size_t)kN * K1P + g] = 0;
  if (g < np2) ab[(size_t)(MP_N + kNLG) * K1P + g] = 0;
  if (g < kN) { m0_cur[g] = 0; mL_cur[g] = 0; }
  if (g < kNLG) lg_cur[g] = 0;
}

// ---------------- CSR build (merged) ----------------

__global__ void k_hist_all(const int* __restrict__ edge_index,
                           const int* __restrict__ lg_map,
                           const int* __restrict__ lg_ei,
                           int* __restrict__ m0_cur, int* __restrict__ mL_cur,
                           int* __restrict__ lg_cur) {
  int g = blockIdx.x * blockDim.x + threadIdx.x;
  if (g < kE) { atomicAdd(&m0_cur[edge_index[kE + g]], 1); return; }
  g -= kE;
  if (g < kNLG) { atomicAdd(&mL_cur[lg_map[kNLG + g]], 1); return; }
  g -= kNLG;
  if (g < kNLG) { atomicAdd(&mL_cur[lg_map[g]], 1); return; }
  g -= kNLG;
  if (g < kELG) atomicAdd(&lg_cur[lg_ei[kELG + g]], 1);
}

__device__ void scan_one(int* cursor, int* offs, int n) {
  __shared__ int part[256];
  int tid = threadIdx.x;
  int chunk = (n + 255) / 256;
  int s0 = tid * chunk;
  int s1 = min(n, s0 + chunk);
  int sum = 0;
  for (int i = s0; i < s1; ++i) sum += cursor[i];
  part[tid] = sum;
  __syncthreads();
  for (int off = 1; off < 256; off <<= 1) {
    int v = (tid >= off) ? part[tid - off] : 0;
    __syncthreads();
    part[tid] += v;
    __syncthreads();
  }
  int run = (tid == 0) ? 0 : part[tid - 1];
  for (int i = s0; i < s1; ++i) {
    int dv = cursor[i];
    offs[i] = run;
    cursor[i] = run;
    run += dv;
  }
  if (tid == 255) offs[n] = run;
}

__global__ __launch_bounds__(256) void k_scan3(
    int* __restrict__ m0_cur, int* __restrict__ m0_offs,
    int* __restrict__ mL_cur, int* __restrict__ mL_offs,
    int* __restrict__ lg_cur, int* __restrict__ lg_offs) {
  if (blockIdx.x == 0) scan_one(m0_cur, m0_offs, kN);
  else if (blockIdx.x == 1) scan_one(mL_cur, mL_offs, kN);
  else scan_one(lg_cur, lg_offs, kNLG);
}

__global__ void k_fill_all(const int* __restrict__ edge_index,
                           const int* __restrict__ lg_map,
                           const int* __restrict__ lg_ei,
                           int* __restrict__ m0_cur, int* __restrict__ m0_perm,
                           int* __restrict__ mL_cur, int* __restrict__ mL_perm,
                           int* __restrict__ lg_cur, int* __restrict__ lg_perm) {
  int g = blockIdx.x * blockDim.x + threadIdx.x;
  if (g < kE) {
    int pos = atomicAdd(&m0_cur[edge_index[kE + g]], 1);
    m0_perm[pos] = g;
    return;
  }
  g -= kE;
  if (g < kNLG) {
    int pos = atomicAdd(&mL_cur[lg_map[kNLG + g]], 1);
    mL_perm[pos] = g;
    return;
  }
  g -= kNLG;
  if (g < kNLG) {
    int pos = atomicAdd(&mL_cur[lg_map[g]], 1);
    mL_perm[pos] = kNLG + g;
    return;
  }
  g -= kNLG;
  if (g < kELG) {
    int pos = atomicAdd(&lg_cur[lg_ei[kELG + g]], 1);
    lg_perm[pos] = g;
  }
}

// ---------------- precompute: self vectors, padded tables, weights ----------------

__global__ void k_selfvec(const float* __restrict__ g1, const float* __restrict__ g2,
                          const float* __restrict__ l1, const float* __restrict__ l2,
                          float* __restrict__ slv) {
  int g = blockIdx.x * blockDim.x + threadIdx.x;
  if (g >= kL * 640) return;
  int l = g / 640, rem = g - l * 640;
  int gr = rem / 320, c = rem - gr * 320;
  float v = 0.f;
  if (c < D) {
    if (gr == 0) v = g1[(size_t)l * 6 * D + 4 * D + c] + g2[(size_t)l * 3 * D + c];
    else         v = l1[(size_t)l * 120 * D + 119 * D + c] + l2[(size_t)l * 3 * D + c];
  }
  slv[g] = v;
}

__device__ void pad_tab_one(const float* T, short* O, int g) {
  int r = g / RH, c = g - r * RH;
  O[g] = (c < D) ? f2h(T[(size_t)r * D + c]) : (short)0;
}

__global__ void k_pad_tab_all(const float* __restrict__ s1, const float* __restrict__ s2,
                              const float* __restrict__ s3, const float* __restrict__ s4,
                              short* __restrict__ o1, short* __restrict__ o2,
                              short* __restrict__ o3, short* __restrict__ o4) {
  int g = blockIdx.x * blockDim.x + threadIdx.x;
  if (g < 6 * RH) { pad_tab_one(s1, o1, g); return; }
  g -= 6 * RH;
  if (g < 3 * RH) { pad_tab_one(s2, o2, g); return; }
  g -= 3 * RH;
  if (g < 120 * RH) { pad_tab_one(s3, o3, g); return; }
  g -= 120 * RH;
  if (g < 3 * RH) pad_tab_one(s4, o4, g);
}

__device__ void cvt_w1(const float* W, short* Wt, int g) {
  int per = N1P * K1P;
  int l = g / per, rem = g - l * per;
  int n = rem / K1P, k = rem - n * K1P;
  float v = (n < 2 * D && k < D) ? W[(size_t)l * D * 2 * D + (size_t)k * 2 * D + n] : 0.f;
  Wt[g] = f2h(v);
}

__device__ void cvt_w2(const float* W, short* Wt, int g) {
  int per = N2P * K2P;
  int l = g / per, rem = g - l * per;
  int n = rem / K2P, k = rem - n * K2P;
  float v = (n < D && k < 2 * D) ? W[(size_t)l * 2 * D * D + (size_t)k * D + n] : 0.f;
  Wt[g] = f2h(v);
}

__global__ void k_convert_wt_all(const float* __restrict__ g_w1, const float* __restrict__ g_w2,
                                 const float* __restrict__ lg_w1, const float* __restrict__ lg_w2,
                                 short* __restrict__ g_w1t, short* __restrict__ g_w2t,
                                 short* __restrict__ lg_w1t, short* __restrict__ lg_w2t) {
  int g = blockIdx.x * blockDim.x + threadIdx.x;
  const int s1 = kL * N1P * K1P, s2 = kL * N2P * K2P;
  if (g < s1) { cvt_w1(g_w1, g_w1t, g); return; }
  g -= s1;
  if (g < s2) { cvt_w2(g_w2, g_w2t, g); return; }
  g -= s2;
  if (g < s1) { cvt_w1(lg_w1, lg_w1t, g); return; }
  g -= s1;
  if (g < s2) cvt_w2(lg_w2, lg_w2t, g);
}

// ---------------- gather kernels ----------------

__global__ void k_gather_all0(
    const uint4* __restrict__ h16, const uint4* __restrict__ e16,
    const int* __restrict__ m_src, const int* __restrict__ eattr,
    const int* __restrict__ x, const int* __restrict__ lg_src,
    const int* __restrict__ map2,
    const uint4* __restrict__ t1m, const uint4* __restrict__ t2m,
    const uint4* __restrict__ t1l, const uint4* __restrict__ t2l,
    const float* __restrict__ slvM, const float* __restrict__ slvL,
    const int* __restrict__ m_offs, const int* __restrict__ m_perm,
    const int* __restrict__ l_offs, const int* __restrict__ l_perm,
    uint4* __restrict__ ab) {
  int node = blockIdx.x * 4 + (threadIdx.x >> 6);
  int lane = threadIdx.x & 63;
  if (node >= kN + kNLG) return;
  bool act = lane < RQ;
  int ll = act ? lane : 0;
  bool isM = node < kN;
  int j = isM ? node : node - kN;
  const uint4* selfrow = isM ? (h16 + (size_t)node * RQ) : (e16 + (size_t)j * RQ);
  const float* sv = (isM ? slvM : slvL) + ll * 8;
  const int* offs = isM ? m_offs : l_offs;
  const int* permp = isM ? m_perm : l_perm;
  const uint4* bA = isM ? h16 : e16;
  const uint4* bT1 = isM ? t1m : t1l;
  const uint4* bT2 = isM ? t2m : t2l;

  float acc[8];
  {
    uint4 s = selfrow[ll];
    float2 t0 = upk(s.x), t1 = upk(s.y), t2 = upk(s.z), t3 = upk(s.w);
    acc[0] = t0.x + sv[0]; acc[1] = t0.y + sv[1];
    acc[2] = t1.x + sv[2]; acc[3] = t1.y + sv[3];
    acc[4] = t2.x + sv[4]; acc[5] = t2.y + sv[5];
    acc[6] = t3.x + sv[6]; acc[7] = t3.y + sv[7];
  }

  int p0 = offs[j], p1 = offs[j + 1];
  for (int pb = p0; pb < p1; pb += 64) {
    int cnt = min(64, p1 - pb);
    int e_ = permp[pb + ((lane < cnt) ? lane : 0)];
    int r1, r2, r3;
    if (isM) {
      r1 = m_src[e_];
      r2 = eattr[2 * e_];
      r3 = eattr[2 * e_ + 1];
    } else {
      r1 = lg_src[e_];
      int a = map2[e_];
      r2 = x[2 * a];
      r3 = x[2 * a + 1];
    }
    int t = 0;
    for (; t + 1 < cnt; t += 2) {
      int a0 = __shfl(r1, t), b0 = __shfl(r2, t), c0 = __shfl(r3, t);
      int a1 = __shfl(r1, t + 1), b1 = __shfl(r2, t + 1), c1 = __shfl(r3, t + 1);
      uint4 x0 = bA[(size_t)a0 * RQ + ll];
      uint4 y0 = bT1[(size_t)b0 * RQ + ll];
      uint4 z0 = bT2[(size_t)c0 * RQ + ll];
      uint4 x1 = bA[(size_t)a1 * RQ + ll];
      uint4 y1 = bT1[(size_t)b1 * RQ + ll];
      uint4 z1 = bT2[(size_t)c1 * RQ + ll];
      addrow(acc, x0); addrow(acc, y0); addrow(acc, z0);
      addrow(acc, x1); addrow(acc, y1); addrow(acc, z1);
    }
    if (t < cnt) {
      int a0 = __shfl(r1, t), b0 = __shfl(r2, t), c0 = __shfl(r3, t);
      uint4 x0 = bA[(size_t)a0 * RQ + ll];
      uint4 y0 = bT1[(size_t)b0 * RQ + ll];
      uint4 z0 = bT2[(size_t)c0 * RQ + ll];
      addrow(acc, x0); addrow(acc, y0); addrow(acc, z0);
    }
  }
  if (act) ab[(size_t)(isM ? node : MP_N + j) * RQ + ll] = pk4(acc);
}

__global__ void k_gather_allL(
    const uint4* __restrict__ h16, const uint4* __restrict__ e16,
    const int* __restrict__ lg_map, const int* __restrict__ lg_src,
    const int* __restrict__ map2,
    const float* __restrict__ slvM, const float* __restrict__ slvL,
    const int* __restrict__ m_offs, const int* __restrict__ m_perm,
    const int* __restrict__ l_offs, const int* __restrict__ l_perm,
    uint4* __restrict__ ab) {
  int node = blockIdx.x * 4 + (threadIdx.x >> 6);
  int lane = threadIdx.x & 63;
  if (node >= kN + kNLG) return;
  bool act = lane < RQ;
  int ll = act ? lane : 0;
  bool isM = node < kN;
  int j = isM ? node : node - kN;
  const uint4* selfrow = isM ? (h16 + (size_t)node * RQ) : (e16 + (size_t)j * RQ);
  const float* sv = (isM ? slvM : slvL) + ll * 8;
  const int* offs = isM ? m_offs : l_offs;
  const int* permp = isM ? m_perm : l_perm;
  const uint4* bA = isM ? h16 : e16;
  const uint4* bB = isM ? e16 : h16;

  float acc[8];
  {
    uint4 s = selfrow[ll];
    float2 t0 = upk(s.x), t1 = upk(s.y), t2 = upk(s.z), t3 = upk(s.w);
    acc[0] = t0.x + sv[0]; acc[1] = t0.y + sv[1];
    acc[2] = t1.x + sv[2]; acc[3] = t1.y + sv[3];
    acc[4] = t2.x + sv[4]; acc[5] = t2.y + sv[5];
    acc[6] = t3.x + sv[6]; acc[7] = t3.y + sv[7];
  }

  int p0 = offs[j], p1 = offs[j + 1];
  for (int pb = p0; pb < p1; pb += 64) {
    int cnt = min(64, p1 - pb);
    int e_ = permp[pb + ((lane < cnt) ? lane : 0)];
    int ra, rb;
    if (isM) {
      ra = lg_map[e_];
      rb = (e_ < kNLG) ? e_ : e_ - kNLG;
    } else {
      ra = lg_src[e_];
      rb = map2[e_];
    }
    int t = 0;
    for (; t + 3 < cnt; t += 4) {
      int a0 = __shfl(ra, t),     b0 = __shfl(rb, t);
      int a1 = __shfl(ra, t + 1), b1 = __shfl(rb, t + 1);
      int a2 = __shfl(ra, t + 2), b2 = __shfl(rb, t + 2);
      int a3 = __shfl(ra, t + 3), b3 = __shfl(rb, t + 3);
      uint4 x0 = bA[(size_t)a0 * RQ + ll];
      uint4 y0 = bB[(size_t)b0 * RQ + ll];
      uint4 x1 = bA[(size_t)a1 * RQ + ll];
      uint4 y1 = bB[(size_t)b1 * RQ + ll];
      uint4 x2 = bA[(size_t)a2 * RQ + ll];
      uint4 y2 = bB[(size_t)b2 * RQ + ll];
      uint4 x3 = bA[(size_t)a3 * RQ + ll];
      uint4 y3 = bB[(size_t)b3 * RQ + ll];
      addrow(acc, x0); addrow(acc, y0);
      addrow(acc, x1); addrow(acc, y1);
      addrow(acc, x2); addrow(acc, y2);
      addrow(acc, x3); addrow(acc, y3);
    }
    for (; t < cnt; ++t) {
      int a0 = __shfl(ra, t), b0 = __shfl(rb, t);
      uint4 x0 = bA[(size_t)a0 * RQ + ll];
      uint4 y0 = bB[(size_t)b0 * RQ + ll];
      addrow(acc, x0); addrow(acc, y0);
    }
  }
  if (act) ab[(size_t)(isM ? node : MP_N + j) * RQ + ll] = pk4(acc);
}

// ---------------- embed ----------------

__global__ void k_embed_pair(const int* __restrict__ idx, const float* __restrict__ t1,
                             const float* __restrict__ t2, float* __restrict__ out,
                             short* __restrict__ hist, int n) {
  int g = blockIdx.x * blockDim.x + threadIdx.x;
  if (g >= n * RH) return;
  int i = g / RH, c = g - i * RH;
  short hv = 0;
  if (c < D) {
    float v = t1[(size_t)idx[2 * i] * D + c] + t2[(size_t)idx[2 * i + 1] * D + c];
    out[(size_t)i * D + c] = v;
    hv = f2h(v);
  }
  hist[g] = hv;
}

// ---------------- dual MFMA GEMM (fp16 out; optional fused BN stats) ----------------

template<bool RELU, bool STATS>
__global__ __launch_bounds__(256) void k_mfma_gemm_dual(
    const short* __restrict__ A,
    const short* __restrict__ BtM, const short* __restrict__ BtL,
    const float* __restrict__ biasM, const float* __restrict__ biasL, int biasN,
    short* __restrict__ Cout, int Ccols, int Cstride, int Kpad,
    int mainLimit, int lgLimit,
    float* __restrict__ statsM, float* __restrict__ statsL) {
  __shared__ __align__(16) short ldsA[128 * 32];
  __shared__ __align__(16) short ldsB[128 * 32];
  __shared__ float sd[256];
  const int tid = threadIdx.x;
  const int lane = tid & 63, w = tid >> 6;
  const bool isMain = (int)blockIdx.y < MAIN_TILES;
  const short* Bt = isMain ? BtM : BtL;
  const float* bias = isMain ? biasM : biasL;
  const int rowLimit = isMain ? mainLimit : lgLimit;
  const int brow = blockIdx.y * 128;
  const int bcol = blockIdx.x * 128;
  const int wr = w >> 1, wc = w & 1;

  if (STATS) sd[tid] = 0.f;

  f32x4 acc[4][4] = {};

  const int sr = tid >> 2;
  const int sc = (tid & 3) * 8;
  char* la = (char*)ldsA + w * 1024;
  char* lb = (char*)ldsB + w * 1024;

  for (int k0 = 0; k0 < Kpad; k0 += 32) {
    __syncthreads();
    const short* gA0 = A + (size_t)(brow + sr) * Kpad + (k0 + sc);
    const short* gB0 = Bt + (size_t)(bcol + sr) * Kpad + (k0 + sc);
    gload_lds16(gA0, la);
    gload_lds16(gA0 + (size_t)64 * Kpad, la + 4096);
    gload_lds16(gB0, lb);
    gload_lds16(gB0 + (size_t)64 * Kpad, lb + 4096);
    __syncthreads();

    const int kq = (lane >> 4) * 16;
    half8 af[4], bf[4];
#pragma unroll
    for (int m = 0; m < 4; ++m) {
      int row = wr * 64 + m * 16 + (lane & 15);
      af[m] = *(const half8*)((const char*)ldsA + row * 64 + kq);
    }
#pragma unroll
    for (int n = 0; n < 4; ++n) {
      int col = wc * 64 + n * 16 + (lane & 15);
      bf[n] = *(const half8*)((const char*)ldsB + col * 64 + kq);
    }
#pragma unroll
    for (int m = 0; m < 4; ++m)
#pragma unroll
      for (int n = 0; n < 4; ++n)
        acc[m][n] = __builtin_amdgcn_mfma_f32_16x16x32_f16(af[m], bf[n], acc[m][n], 0, 0, 0);
  }

  const int r0 = brow + wr * 64;
  const int c0 = bcol + wc * 64;
  float ps[4] = {}, pq[4] = {};
#pragma unroll
  for (int m = 0; m < 4; ++m) {
#pragma unroll
    for (int i = 0; i < 4; ++i) {
      int row = r0 + m * 16 + (lane >> 4) * 4 + i;
      bool rv = row < rowLimit;
#pragma unroll
      for (int n = 0; n < 4; ++n) {
        int col = c0 + n * 16 + (lane & 15);
        float bv = (col < biasN) ? bias[col] : 0.f;
        float v = acc[m][n][i] + bv;
        if (RELU) v = fmaxf(v, 0.f);
        if (rv && col < Ccols) {
          Cout[(size_t)row * Cstride + col] = f2h(v);
          if (STATS) { ps[n] += v; pq[n] += v * v; }
        }
      }
    }
  }

  if (STATS) {
#pragma unroll
    for (int n = 0; n < 4; ++n) {
      float s = ps[n], q = pq[n];
      s += __shfl_xor(s, 16); q += __shfl_xor(q, 16);
      s += __shfl_xor(s, 32); q += __shfl_xor(q, 32);
      if ((lane >> 4) == 0) {
        int c = wc * 64 + n * 16 + (lane & 15);
        atomicAdd(&sd[c], s);
        atomicAdd(&sd[128 + c], q);
      }
    }
    __syncthreads();
    float* gs = isMain ? statsM : statsL;
    if (tid < 128) {
      int col = bcol + tid;
      if (col < Ccols) {
        atomicAdd(&gs[col], sd[tid]);
        atomicAdd(&gs[D + col], sd[128 + tid]);
      }
    }
  }
}

// ---------------- merged batchnorm apply (reads fp16 preact) ----------------

template<bool WRITE_HIST>
__global__ void k_bn_apply_all(const short* __restrict__ pre, float* __restrict__ Xout,
                               short* __restrict__ hist,
                               const float* __restrict__ statsM,
                               const float* __restrict__ statsL,
                               const float* __restrict__ gM, const float* __restrict__ bM,
                               const float* __restrict__ gL, const float* __restrict__ bL,
                               int relu) {
  int g = blockIdx.x * blockDim.x + threadIdx.x;
  if (g >= (kN + kNLG) * RH) return;
  int r = g / RH;
  int c = g - r * RH;
  short hv = 0;
  if (c < D) {
    bool m = r < kN;
    int pr = m ? r : MP_N + (r - kN);
    const float* s = m ? statsM : statsL;
    float inv_n = m ? (1.f / kN) : (1.f / kNLG);
    float mu = s[c] * inv_n;
    float var = s[D + c] * inv_n - mu * mu;
    float rs = rsqrtf(var + 1e-5f);
    float gam = (m ? gM : gL)[c];
    float bet = (m ? bM : bL)[c];
    float v = (h2f(pre[(size_t)pr * N2P + c]) - mu) * rs * gam + bet;
    if (relu) v = fmaxf(v, 0.f);
    Xout[(size_t)r * D + c] = v;
    hv = f2h(v);
  }
  if (WRITE_HIST) hist[g] = hv;
}

}  // namespace

extern "C" void kernel_launch(void* const* d_in, const int* in_sizes, int n_in,
                              void* d_out_v, int out_size, void* d_ws, size_t ws_size,
                              hipStream_t stream) {
  const int*   x            = (const int*)d_in[0];
  const int*   edge_index   = (const int*)d_in[1];
  const int*   edge_attr    = (const int*)d_in[2];
  const int*   lg_x         = (const int*)d_in[3];
  const int*   lg_edge_index= (const int*)d_in[4];
  const int*   lg_map       = (const int*)d_in[5];
  const int*   lg_map2      = (const int*)d_in[6];
  const float* node_emb1    = (const float*)d_in[7];
  const float* node_emb2    = (const float*)d_in[8];
  const float* gnn_e_emb1   = (const float*)d_in[9];
  const float* gnn_e_emb2   = (const float*)d_in[10];
  const float* g_emb1       = (const float*)d_in[11];
  const float* g_emb2       = (const float*)d_in[12];
  const float* g_w1         = (const float*)d_in[13];
  const float* g_b1         = (const float*)d_in[14];
  const float* g_w2         = (const float*)d_in[15];
  const float* g_b2         = (const float*)d_in[16];
  const float* g_gamma      = (const float*)d_in[17];
  const float* g_beta       = (const float*)d_in[18];
  const float* lg_emb1      = (const float*)d_in[19];
  const float* lg_emb2      = (const float*)d_in[20];
  const float* lg_w1        = (const float*)d_in[21];
  const float* lg_b1        = (const float*)d_in[22];
  const float* lg_w2        = (const float*)d_in[23];
  const float* lg_b2        = (const float*)d_in[24];
  const float* lg_gamma     = (const float*)d_in[25];
  const float* lg_beta      = (const float*)d_in[26];

  float* out = (float*)d_out_v;
  char*  ws  = (char*)d_ws;

  size_t off = 0;
  auto alloc = [&](size_t bytes) { void* p = ws + off; off = (off + bytes + 255) & ~(size_t)255; return p; };
  short* ab      = (short*)alloc((size_t)MP_ALL * K1P * 2);          // 38.5 MB
  short* hidden  = (short*)alloc((size_t)MP_ALL * N1P * 2);          // 77 MB
  short* pre16   = (short*)alloc((size_t)MP_ALL * N2P * 2);          // 46 MB
  short* hist16  = (short*)alloc((size_t)(kL + 1) * 60000 * RH * 2); // 230 MB
  short* g_w1t   = (short*)alloc((size_t)kL * N1P * K1P * 2);
  short* g_w2t   = (short*)alloc((size_t)kL * N2P * K2P * 2);
  short* lg_w1t  = (short*)alloc((size_t)kL * N1P * K1P * 2);
  short* lg_w2t  = (short*)alloc((size_t)kL * N2P * K2P * 2);
  float* stats   = (float*)alloc(kL * 1200 * 4);
  float* slv     = (float*)alloc(kL * 640 * 4);
  short* t1m     = (short*)alloc(6 * RH * 2);
  short* t2m     = (short*)alloc(3 * RH * 2);
  short* t1l     = (short*)alloc(120 * RH * 2);
  short* t2l     = (short*)alloc(3 * RH * 2);
  int* m0_offs = (int*)alloc((kN + 1) * 4);
  int* m0_cur  = (int*)alloc(kN * 4);
  int* m0_perm = (int*)alloc(kE * 4);
  int* mL_offs = (int*)alloc((kN + 1) * 4);
  int* mL_cur  = (int*)alloc(kN * 4);
  int* mL_perm = (int*)alloc(2 * kNLG * 4);
  int* lg_offs = (int*)alloc((kNLG + 1) * 4);
  int* lg_cur  = (int*)alloc(kNLG * 4);
  int* lg_perm = (int*)alloc(kELG * 4);

  auto hptr  = [&](int l) { return out + (size_t)l * 60000 * D; };
  auto h16p  = [&](int l) { return hist16 + (size_t)l * 60000 * RH; };
  auto e16p  = [&](int l) { return hist16 + ((size_t)l * 60000 + kN) * RH; };

  dim3 b(256);

  // ---- prologue: init, CSR, precompute (9 dispatches) ----
  k_init<<<(kNLG + 255) / 256, b, 0, stream>>>(stats, ab, m0_cur, mL_cur, lg_cur);
  {
    int tot = kE + 2 * kNLG + kELG;
    k_hist_all<<<(tot + 255) / 256, b, 0, stream>>>(edge_index, lg_map, lg_edge_index,
                                                    m0_cur, mL_cur, lg_cur);
    k_scan3<<<3, b, 0, stream>>>(m0_cur, m0_offs, mL_cur, mL_offs, lg_cur, lg_offs);
    k_fill_all<<<(tot + 255) / 256, b, 0, stream>>>(edge_index, lg_map, lg_edge_index,
                                                    m0_cur, m0_perm, mL_cur, mL_perm,
                                                    lg_cur, lg_perm);
  }
  k_selfvec<<<(kL * 640 + 255) / 256, b, 0, stream>>>(g_emb1, g_emb2, lg_emb1, lg_emb2, slv);
  k_pad_tab_all<<<(132 * RH + 255) / 256, b, 0, stream>>>(g_emb1, g_emb2, lg_emb1, lg_emb2,
                                                          t1m, t2m, t1l, t2l);
  {
    int tot = 2 * kL * (N1P * K1P + N2P * K2P);
    k_convert_wt_all<<<(tot + 255) / 256, b, 0, stream>>>(g_w1, g_w2, lg_w1, lg_w2,
                                                          g_w1t, g_w2t, lg_w1t, lg_w2t);
  }
  k_embed_pair<<<(kN * RH + 255) / 256, b, 0, stream>>>(x, node_emb1, node_emb2,
                                                        hptr(0), h16p(0), kN);
  k_embed_pair<<<(kNLG * RH + 255) / 256, b, 0, stream>>>(lg_x, gnn_e_emb1, gnn_e_emb2,
                                                          hptr(0) + (size_t)kN * D,
                                                          e16p(0), kNLG);

  for (int l = 0; l < kL; ++l) {
    int relu_tail = (l < kL - 1) ? 1 : 0;
    float* slot = stats + (size_t)l * 1200;
    const float* slvM = slv + (size_t)l * 640;
    const float* slvL = slvM + 320;

    if (l == 0)
      k_gather_all0<<<(kN + kNLG + 3) / 4, b, 0, stream>>>(
          (const uint4*)h16p(0), (const uint4*)e16p(0),
          edge_index, edge_attr, x, lg_edge_index, lg_map2,
          (const uint4*)t1m, (const uint4*)t2m, (const uint4*)t1l, (const uint4*)t2l,
          slvM, slvL, m0_offs, m0_perm, lg_offs, lg_perm, (uint4*)ab);
    else
      k_gather_allL<<<(kN + kNLG + 3) / 4, b, 0, stream>>>(
          (const uint4*)h16p(l), (const uint4*)e16p(l),
          lg_map, lg_edge_index, lg_map2,
          slvM, slvL, mL_offs, mL_perm, lg_offs, lg_perm, (uint4*)ab);

    k_mfma_gemm_dual<true, false><<<dim3(N1P / 128, MP_ALL / 128), b, 0, stream>>>(
        ab, g_w1t + (size_t)l * N1P * K1P, lg_w1t + (size_t)l * N1P * K1P,
        g_b1 + (size_t)l * 2 * D, lg_b1 + (size_t)l * 2 * D, 2 * D,
        hidden, N1P, N1P, K1P, MP_ALL, MP_ALL, nullptr, nullptr);

    k_mfma_gemm_dual<false, true><<<dim3(N2P / 128, MP_ALL / 128), b, 0, stream>>>(
        hidden, g_w2t + (size_t)l * N2P * K2P, lg_w2t + (size_t)l * N2P * K2P,
        g_b2 + (size_t)l * D, lg_b2 + (size_t)l * D, D,
        pre16, D, N2P, K2P, kN, MP_N + kNLG,
        slot, slot + 600);

    if (l < kL - 1)
      k_bn_apply_all<true><<<((kN + kNLG) * RH + 255) / 256, b, 0, stream>>>(
          pre16, hptr(l + 1), h16p(l + 1), slot, slot + 600,
          g_gamma + (size_t)l * D, g_beta + (size_t)l * D,
          lg_gamma + (size_t)l * D, lg_beta + (size_t)l * D, relu_tail);
    else
      k_bn_apply_all<false><<<((kN + kNLG) * RH + 255) / 256, b, 0, stream>>>(
          pre16, hptr(l + 1), h16p(l + 1), slot, slot + 600,
          g_gamma + (size_t)l * D, g_beta + (size_t)l * D,
          lg_gamma + (size_t)l * D, lg_beta + (size_t)l * D, relu_tail);
  }
}